// Round 2
// baseline (292.127 us; speedup 1.0000x reference)
//
#include <hip/hip_runtime.h>
#include <hip/hip_bf16.h>
#include <cmath>

#define NB 4
#define NS 1024
#define ND 1024
#define NH 16
#define NDH 64
#define NKSP 32
#define SCALE 0.125f      // 1/sqrt(64)
#define LOG2E 1.44269504f
#define SCALE2 (SCALE * LOG2E)

typedef __attribute__((ext_vector_type(8))) short bf16x8;
typedef __attribute__((ext_vector_type(4))) float f32x4;
typedef unsigned long long u64;

#define AS1 __attribute__((address_space(1)))
#define AS3 __attribute__((address_space(3)))

__device__ __forceinline__ void gl_lds16(const void* g, void* l) {
    __builtin_amdgcn_global_load_lds((const AS1 void*)g, (AS3 void*)l, 16, 0, 0);
}

__device__ __forceinline__ ushort f2bf(float f) {
    union { __hip_bfloat16 h; ushort u; } cv;
    cv.h = __float2bfloat16(f);
    return cv.u;
}
__device__ __forceinline__ float bf2f(ushort u) {
    union { unsigned int i; float f; } cv;
    cv.i = ((unsigned int)u) << 16;
    return cv.f;
}
__device__ __forceinline__ float fexp2(float x) {
    return __builtin_amdgcn_exp2f(x);   // v_exp_f32 (base-2)
}

// ---------------------------------------------------------------------------
// y=0: x->bf16 (4096 blocks); y=1..4: W->bf16 (1024 blocks);
// y=5: pack pmask into bitwords (4096 blocks, one wave per u64 word).
// ---------------------------------------------------------------------------
__global__ __launch_bounds__(256)
void f2bf_multi(const float* __restrict__ x,
                const float* __restrict__ w0, const float* __restrict__ w1,
                const float* __restrict__ w2, const float* __restrict__ w3,
                const int* __restrict__ pm,
                ushort* __restrict__ xo,
                ushort* __restrict__ o0, ushort* __restrict__ o1,
                ushort* __restrict__ o2, ushort* __restrict__ o3,
                u64* __restrict__ bm)
{
    int y = blockIdx.y;
    if (y == 5) {
        int word = blockIdx.x * 4 + (threadIdx.x >> 6);
        int lane = threadIdx.x & 63;
        int row  = word >> 4, wcol = word & 15;
        int v = pm[(size_t)row * NS + wcol * 64 + lane];
        u64 b = __ballot(v != 0);
        if (lane == 0) bm[word] = b;
        return;
    }
    const float* src; ushort* dst; int nblk;
    if (y == 0)      { src = x;  dst = xo; nblk = 4096; }
    else if (y == 1) { src = w0; dst = o0; nblk = 1024; }
    else if (y == 2) { src = w1; dst = o1; nblk = 1024; }
    else if (y == 3) { src = w2; dst = o2; nblk = 1024; }
    else             { src = w3; dst = o3; nblk = 1024; }
    if (blockIdx.x >= (unsigned)nblk) return;
    int i = (blockIdx.x * 256 + threadIdx.x) * 4;
    float4 v = *(const float4*)&src[i];
    ushort4 o;
    o.x = f2bf(v.x); o.y = f2bf(v.y); o.z = f2bf(v.z); o.w = f2bf(v.w);
    *(ushort4*)&dst[i] = o;
}

// ---------------------------------------------------------------------------
// Fused QKV GEMM (direct-scatter epilogue; V also writes Vt).
// grid (24,32): blockIdx.x: [0,8)=Q [8,16)=K [16,24)=V.
// ---------------------------------------------------------------------------
__global__ __launch_bounds__(256)
void gemm_qkv(const ushort* __restrict__ xb,
              const ushort* __restrict__ Wqb, const ushort* __restrict__ Wkb,
              const ushort* __restrict__ Wvb,
              const float* __restrict__ bq, const float* __restrict__ bk,
              const float* __restrict__ bv,
              ushort* __restrict__ Qo, ushort* __restrict__ Ko,
              ushort* __restrict__ Vo, ushort* __restrict__ Vto)
{
    constexpr int K = ND;
    __shared__ __attribute__((aligned(16))) ushort As[128 * 32];
    __shared__ __attribute__((aligned(16))) ushort Bs[128 * 32];

    const int tid  = threadIdx.x;
    const int lane = tid & 63, w = tid >> 6;
    const int wm = w >> 1, wn = w & 1;
    const int which = blockIdx.x >> 3;
    const int n0 = (blockIdx.x & 7) * 128;
    const int m0 = blockIdx.y * 128;
    const int quad = lane >> 4, l16 = lane & 15;

    const ushort* W = (which == 0) ? Wqb : (which == 1) ? Wkb : Wvb;
    const float* bias = (which == 0) ? bq : (which == 1) ? bk : bv;
    ushort* Out = (which == 0) ? Qo : (which == 1) ? Ko : Vo;

    f32x4 acc[4][4] = {};

    for (int k0 = 0; k0 < K; k0 += 32) {
        __syncthreads();
#pragma unroll
        for (int u = 0; u < 2; ++u) {
            int t0 = u * 256 + w * 64;
            int t  = t0 + lane;
            int row = t >> 2, kc = (t & 3) * 8;
            gl_lds16(xb + (size_t)(m0 + row) * K + k0 + kc, &As[t0 * 8]);
            gl_lds16(W  + (size_t)(n0 + row) * K + k0 + kc, &Bs[t0 * 8]);
        }
        __syncthreads();

        bf16x8 af[4], bfr[4];
#pragma unroll
        for (int mt = 0; mt < 4; ++mt)
            af[mt] = *(const bf16x8*)&As[(wm*64 + mt*16 + l16) * 32 + quad*8];
#pragma unroll
        for (int nt = 0; nt < 4; ++nt)
            bfr[nt] = *(const bf16x8*)&Bs[(wn*64 + nt*16 + l16) * 32 + quad*8];
#pragma unroll
        for (int mt = 0; mt < 4; ++mt)
#pragma unroll
            for (int nt = 0; nt < 4; ++nt)
                acc[mt][nt] = __builtin_amdgcn_mfma_f32_16x16x32_bf16(
                    af[mt], bfr[nt], acc[mt][nt], 0, 0, 0);
    }

#pragma unroll
    for (int nt = 0; nt < 4; ++nt) {
        int n = n0 + wn*64 + nt*16 + l16;
        float bz = bias[n];
        int hh = n >> 6, dh = n & 63;
#pragma unroll
        for (int mt = 0; mt < 4; ++mt) {
#pragma unroll
            for (int rg = 0; rg < 4; ++rg) {
                int m = m0 + wm*64 + mt*16 + quad*4 + rg;
                int b = m >> 10, s = m & (NS - 1);
                ushort val = f2bf(acc[mt][nt][rg] + bz);
                Out[(((size_t)(b*NH + hh))*NS + s)*NDH + dh] = val;
                if (which == 2)
                    Vto[(((size_t)(b*NH + hh))*NDH + dh)*NS + s] = val;
            }
        }
    }
}

// ---------------------------------------------------------------------------
// Output GEMM: 64x128 tile -> 512 blocks.
// ---------------------------------------------------------------------------
__global__ __launch_bounds__(256)
void gemm_out(const ushort* __restrict__ A, const ushort* __restrict__ W,
              const float* __restrict__ bias, float* __restrict__ Cout)
{
    constexpr int K = ND;
    __shared__ __attribute__((aligned(16))) ushort As[64 * 32];
    __shared__ __attribute__((aligned(16))) ushort Bs[128 * 32];

    const int tid  = threadIdx.x;
    const int lane = tid & 63, w = tid >> 6;
    const int wm = w & 1, wn = w >> 1;
    const int m0 = blockIdx.y * 64, n0 = blockIdx.x * 128;
    const int quad = lane >> 4, l16 = lane & 15;

    f32x4 acc[2][4] = {};

    for (int k0 = 0; k0 < K; k0 += 32) {
        __syncthreads();
        {
            int t0 = w * 64;
            int t  = t0 + lane;
            int row = t >> 2, kc = (t & 3) * 8;
            gl_lds16(A + (size_t)(m0 + row) * K + k0 + kc, &As[t0 * 8]);
        }
#pragma unroll
        for (int u = 0; u < 2; ++u) {
            int t0 = u * 256 + w * 64;
            int t  = t0 + lane;
            int row = t >> 2, kc = (t & 3) * 8;
            gl_lds16(W + (size_t)(n0 + row) * K + k0 + kc, &Bs[t0 * 8]);
        }
        __syncthreads();

        bf16x8 af[2], bfr[4];
#pragma unroll
        for (int mt = 0; mt < 2; ++mt)
            af[mt] = *(const bf16x8*)&As[(wm*32 + mt*16 + l16) * 32 + quad*8];
#pragma unroll
        for (int nt = 0; nt < 4; ++nt)
            bfr[nt] = *(const bf16x8*)&Bs[(wn*64 + nt*16 + l16) * 32 + quad*8];
#pragma unroll
        for (int mt = 0; mt < 2; ++mt)
#pragma unroll
            for (int nt = 0; nt < 4; ++nt)
                acc[mt][nt] = __builtin_amdgcn_mfma_f32_16x16x32_bf16(
                    af[mt], bfr[nt], acc[mt][nt], 0, 0, 0);
    }

#pragma unroll
    for (int nt = 0; nt < 4; ++nt) {
        int n = n0 + wn*64 + nt*16 + l16;
        float bz = bias[n];
#pragma unroll
        for (int mt = 0; mt < 2; ++mt) {
#pragma unroll
            for (int rg = 0; rg < 4; ++rg) {
                int m = m0 + wm*32 + mt*16 + quad*4 + rg;
                Cout[(size_t)m * ND + n] = acc[mt][nt][rg] + bz;
            }
        }
    }
}

// ---------------------------------------------------------------------------
// MFMA flash attention, 128 q-rows/block, 512 threads (8 waves), grid 512.
// Post-mortem r1: 64-row/1024-block config regressed (82.7->93.6us) because
// 4 blocks/CU = 4 distinct heads = 64KB of K/V tiles > 32KB L1 -> thrash,
// and total fragment-gather instructions doubled. r2 keeps blocks/CU <= 2
// (<=2 heads, 32KB, L1-resident) while doubling waves/SIMD via 8-wave
// blocks: tail (dense-only, the critical phase) goes 1 -> 2 waves/SIMD.
// - 8 waves read IDENTICAL K/V addresses; raw s_barrier per kt keeps them
//   in lockstep so L1/MSHR serves 7 of 8 (no vmcnt drain: not __syncthreads).
// - kf double-buffered in regs: kt+1's K fragments issued a full iteration
//   early. vf issued at top of each step (hidden under QK+exp slack).
// - MW re-laid out as [kt][row]: the per-kt mask word read is now
//   conflict-free (was a 16-way-conflict ds_read_b64).
// - __launch_bounds__(512,4) caps VGPR at 128 so 2 blocks/CU stay legal.
// Dense math unchanged: S^T mfma(kf,qf); base-2 exp; lsum via ones-MFMA;
// no max subtraction (scores bounded). Sparse: scalar fp32, 8 waves.
// LDS = Ps 18432 + MW 16384 = 34.8 KB.
// ---------------------------------------------------------------------------
#define LOADK(DST, KT)                                                        \
    _Pragma("unroll")                                                         \
    for (int nt = 0; nt < 4; ++nt)                                            \
        _Pragma("unroll")                                                     \
        for (int kk = 0; kk < 2; ++kk)                                        \
            DST[nt][kk] = *(const bf16x8*)                                    \
                &Kh[(size_t)((KT)*64 + nt*16 + l16) * NDH + kk*32 + quad*8];

#define LOADV(DST, KT)                                                        \
    _Pragma("unroll")                                                         \
    for (int nt = 0; nt < 4; ++nt)                                            \
        _Pragma("unroll")                                                     \
        for (int kk = 0; kk < 2; ++kk)                                        \
            DST[nt][kk] = *(const bf16x8*)                                    \
                &Vth[(size_t)(nt*16 + l16) * NS + (KT)*64 + kk*32 + quad*8];

#define STEP(KT, KF, VF)                                                      \
    {                                                                         \
        u64 wq = MW[(KT)*128 + qrow] >> (quad * 4);                           \
        f32x4 s_acc[4] = {};                                                  \
        __builtin_amdgcn_s_setprio(1);                                        \
        _Pragma("unroll")                                                     \
        for (int nt = 0; nt < 4; ++nt)                                        \
            _Pragma("unroll")                                                 \
            for (int kk = 0; kk < 2; ++kk)                                    \
                s_acc[nt] = __builtin_amdgcn_mfma_f32_16x16x32_bf16(          \
                    KF[nt][kk], qf[kk], s_acc[nt], 0, 0, 0);                  \
        __builtin_amdgcn_s_setprio(0);                                        \
        _Pragma("unroll")                                                     \
        for (int nt = 0; nt < 4; ++nt) {                                      \
            ushort4 pk;                                                       \
            float p0 = fexp2(fmaf(s_acc[nt][0], SCALE2,                       \
                 ((wq >> (nt*16 + 0)) & 1ULL) ? 0.f : nlam2));                \
            float p1 = fexp2(fmaf(s_acc[nt][1], SCALE2,                       \
                 ((wq >> (nt*16 + 1)) & 1ULL) ? 0.f : nlam2));                \
            float p2 = fexp2(fmaf(s_acc[nt][2], SCALE2,                       \
                 ((wq >> (nt*16 + 2)) & 1ULL) ? 0.f : nlam2));                \
            float p3 = fexp2(fmaf(s_acc[nt][3], SCALE2,                       \
                 ((wq >> (nt*16 + 3)) & 1ULL) ? 0.f : nlam2));                \
            pk.x = f2bf(p0); pk.y = f2bf(p1);                                 \
            pk.z = f2bf(p2); pk.w = f2bf(p3);                                 \
            *(ushort4*)&Ps[qrow*72 + nt*16 + quad*4] = pk;                    \
        }                                                                     \
        bf16x8 pf[2];                                                         \
        _Pragma("unroll")                                                     \
        for (int kk = 0; kk < 2; ++kk)                                        \
            pf[kk] = *(const bf16x8*)&Ps[qrow*72 + kk*32 + quad*8];           \
        __builtin_amdgcn_s_setprio(1);                                        \
        _Pragma("unroll")                                                     \
        for (int kk = 0; kk < 2; ++kk) {                                      \
            l_acc = __builtin_amdgcn_mfma_f32_16x16x32_bf16(                  \
                pf[kk], ones.v, l_acc, 0, 0, 0);                              \
            _Pragma("unroll")                                                 \
            for (int nt = 0; nt < 4; ++nt)                                    \
                o_acc[nt] = __builtin_amdgcn_mfma_f32_16x16x32_bf16(          \
                    pf[kk], VF[nt][kk], o_acc[nt], 0, 0, 0);                  \
        }                                                                     \
        __builtin_amdgcn_s_setprio(0);                                        \
    }

__global__ __launch_bounds__(512, 4)
void attn_kernel(const ushort* __restrict__ Qb, const ushort* __restrict__ Kb,
                 const ushort* __restrict__ Vb, const ushort* __restrict__ Vt,
                 const u64* __restrict__ bm,
                 const int* __restrict__ pidx, const int* __restrict__ pimask,
                 const float* __restrict__ u_prev, ushort* __restrict__ OA)
{
    __shared__ __attribute__((aligned(16))) ushort Ps[128 * 72];
    __shared__ __attribute__((aligned(16))) u64    MW[16 * 128];

    const int tid  = threadIdx.x;
    const int lane = tid & 63, w = tid >> 6;          // w: 0..7
    const int quad = lane >> 4, l16 = lane & 15;

    const int id    = blockIdx.x;         // 0..511
    const int xcd   = id & 7;
    const int t5    = id >> 3;            // 0..63
    const int qtile = t5 & 7;             // 8 tiles of 128 rows
    const int head  = (t5 >> 3) * 8 + xcd;
    const int b = head >> 4, h = head & 15;
    const int s0 = qtile * 128;

    const float lam = 10.0f * __expf(-5.0f * u_prev[b]);
    const bool sparse = (lam >= 1.0f);

    const size_t bh = (size_t)b * NH + h;
    const ushort* Qh  = Qb + bh * NS * NDH;
    const ushort* Kh  = Kb + bh * NS * NDH;
    const ushort* Vh  = Vb + bh * NS * NDH;
    const ushort* Vth = Vt + bh * NDH * NS;

    if (!sparse) {
        const float nlam2 = -lam * LOG2E;   // base-2 bias

        // stage mask words for rows s0..s0+127 as MW[kt][row] (16 KB)
#pragma unroll
        for (int u = 0; u < 4; ++u) {
            int idx = u * 512 + tid;              // 0..2047
            int row = idx >> 4, wd = idx & 15;
            MW[wd * 128 + row] = bm[(size_t)s0 * 16 + idx];
        }
        __syncthreads();   // the only full barrier (LDS visibility)

        const int qrow = w*16 + l16;      // this wave's 16 q-rows

        // Q fragments (serve as B-operand = Q^T)
        bf16x8 qf[2];
#pragma unroll
        for (int kk = 0; kk < 2; ++kk)
            qf[kk] = *(const bf16x8*)
                &Qh[(size_t)(s0 + qrow) * NDH + kk*32 + quad*8];

        union { bf16x8 v; ushort s[8]; } ones;
#pragma unroll
        for (int i = 0; i < 8; ++i) ones.s[i] = 0x3F80;  // bf16 1.0

        f32x4 o_acc[4] = {};
        f32x4 l_acc = {};

        // software-pipelined K fragments: kfA holds kt, kfB holds kt+1
        bf16x8 kfA[4][2], kfB[4][2], vf[4][2];
        LOADK(kfA, 0);

        for (int kt = 0; kt < 16; kt += 2) {
            __builtin_amdgcn_s_barrier();   // lockstep (no vmcnt drain)
            LOADV(vf, kt);
            LOADK(kfB, kt + 1);
            STEP(kt, kfA, vf);

            __builtin_amdgcn_s_barrier();
            LOADV(vf, kt + 1);
            if (kt + 2 < 16) LOADK(kfA, kt + 2);
            STEP(kt + 1, kfB, vf);
        }

        // epilogue (o_acc: row=query quad*4+rg, col=dh nt*16+l16)
        float inv[4];
#pragma unroll
        for (int rg = 0; rg < 4; ++rg) inv[rg] = 1.f / l_acc[rg];
#pragma unroll
        for (int nt = 0; nt < 4; ++nt)
#pragma unroll
            for (int rg = 0; rg < 4; ++rg) {
                int m = w*16 + quad*4 + rg;
                OA[((size_t)b*NS + s0 + m)*ND + h*NDH + nt*16 + l16] =
                    f2bf(o_acc[nt][rg] * inv[rg]);
            }
    } else {
        // ---------------- sparse path (fp32 scalar, bf16 inputs) ----------
        const int r2  = lane & 15;
        const int cg  = lane >> 4;
        {
            const int row = w*16 + r2;            // 0..127

            float qreg[64];
            {
                const ushort* qp = Qh + (size_t)(s0 + row) * NDH;
#pragma unroll
                for (int c = 0; c < 8; ++c) {
                    union { bf16x8 v; ushort s[8]; } qv;
                    qv.v = *(const bf16x8*)(qp + c*8);
#pragma unroll
                    for (int j = 0; j < 8; ++j) qreg[c*8 + j] = bf2f(qv.s[j]);
                }
            }

            float sc[8];
#pragma unroll
            for (int jj = 0; jj < 8; ++jj) {
                int j  = cg*8 + jj;
                int mv = pimask[(size_t)(s0+row)*NKSP + j];
                if (mv) {
                    int kv = pidx[(size_t)(s0+row)*NKSP + j];
                    const ushort* krow = &Kh[(size_t)kv * NDH];
                    float acc = 0.f;
#pragma unroll
                    for (int c = 0; c < 8; ++c) {
                        union { bf16x8 v; ushort s[8]; } kk;
                        kk.v = *(const bf16x8*)(krow + c*8);
#pragma unroll
                        for (int jb = 0; jb < 8; ++jb)
                            acc = fmaf(qreg[c*8 + jb], bf2f(kk.s[jb]), acc);
                    }
                    sc[jj] = acc * SCALE;
                } else {
                    sc[jj] = -INFINITY;
                }
            }
            float mt = sc[0];
#pragma unroll
            for (int jj = 1; jj < 8; ++jj) mt = fmaxf(mt, sc[jj]);
            mt = fmaxf(mt, __shfl_xor(mt, 16));
            mt = fmaxf(mt, __shfl_xor(mt, 32));

            float psum = 0.f;
#pragma unroll
            for (int jj = 0; jj < 8; ++jj) {
                float p = __expf(sc[jj] - mt);
                psum += p;
                Ps[row * 72 + cg*8 + jj] = f2bf(p);
            }
            psum += __shfl_xor(psum, 16);
            psum += __shfl_xor(psum, 32);

            float o[16];
#pragma unroll
            for (int i = 0; i < 16; ++i) o[i] = 0.f;

            for (int j = 0; j < 32; ++j) {
                float p = bf2f(Ps[row * 72 + j]);
                if (p != 0.f) {
                    int kv = pidx[(size_t)(s0+row)*NKSP + j];
                    const ushort* vrow = &Vh[(size_t)kv * NDH + cg*16];
#pragma unroll
                    for (int c = 0; c < 2; ++c) {
                        union { bf16x8 v; ushort s[8]; } vv;
                        vv.v = *(const bf16x8*)(vrow + c*8);
#pragma unroll
                        for (int jb = 0; jb < 8; ++jb)
                            o[c*8 + jb] = fmaf(p, bf2f(vv.s[jb]), o[c*8 + jb]);
                    }
                }
            }

            float inv = 1.f / psum;
            ushort* op = OA + ((size_t)b*NS + s0 + row)*ND + h*NDH + cg*16;
#pragma unroll
            for (int i4 = 0; i4 < 4; ++i4) {
                ushort4 v;
                v.x = f2bf(o[i4*4+0]*inv); v.y = f2bf(o[i4*4+1]*inv);
                v.z = f2bf(o[i4*4+2]*inv); v.w = f2bf(o[i4*4+3]*inv);
                *(ushort4*)(op + i4*4) = v;
            }
        }
    }
}

// ---------------------------------------------------------------------------
extern "C" void kernel_launch(void* const* d_in, const int* in_sizes, int n_in,
                              void* d_out, int out_size, void* d_ws, size_t ws_size,
                              hipStream_t stream)
{
    const float* x      = (const float*)d_in[0];
    const int*   pmask  = (const int*)  d_in[1];
    const int*   pidx   = (const int*)  d_in[2];
    const int*   pimask = (const int*)  d_in[3];
    const float* u_prev = (const float*)d_in[4];
    const float* Wq     = (const float*)d_in[5];
    const float* bq     = (const float*)d_in[6];
    const float* Wk     = (const float*)d_in[7];
    const float* bk     = (const float*)d_in[8];
    const float* Wv     = (const float*)d_in[9];
    const float* bv     = (const float*)d_in[10];
    const float* Wo     = (const float*)d_in[11];
    const float* bo     = (const float*)d_in[12];
    float* out = (float*)d_out;

    const size_t QSZ = (size_t)NB * NH * NS * NDH;   // 4,194,304 elements
    const size_t WSZ = (size_t)ND * ND;              // 1,048,576 elements
    ushort* xb  = (ushort*)d_ws;        // bf16 x              (8 MB)
    ushort* Qw  = xb  + QSZ;            // bf16 Q (b,h,s,dh)   (8 MB)
    ushort* Kw  = Qw  + QSZ;            // bf16 K              (8 MB)
    ushort* Vw  = Kw  + QSZ;            // bf16 V              (8 MB)
    ushort* Vtw = Vw  + QSZ;            // bf16 V^T (b,h,dh,s) (8 MB)
    ushort* Awb = Vtw + QSZ;            // bf16 attn out       (8 MB)
    ushort* Wqb = Awb + QSZ;            // bf16 weights (2 MB each)
    ushort* Wkb = Wqb + WSZ;
    ushort* Wvb = Wkb + WSZ;
    ushort* Wob = Wvb + WSZ;
    u64*    bmw = (u64*)(Wob + WSZ);    // packed mask (128 KB)

    f2bf_multi<<<dim3(4096, 6), 256, 0, stream>>>(
        x, Wq, Wk, Wv, Wo, pmask, xb, Wqb, Wkb, Wvb, Wob, bmw);

    gemm_qkv<<<dim3(24, 32), 256, 0, stream>>>(
        xb, Wqb, Wkb, Wvb, bq, bk, bv, Qw, Kw, Vw, Vtw);

    attn_kernel<<<512, 512, 0, stream>>>(
        Qw, Kw, Vw, Vtw, bmw, pidx, pimask, u_prev, Awb);

    gemm_out<<<dim3(ND/128, (NB*NS)/64), 256, 0, stream>>>(Awb, Wob, bo, out);
}

// Round 3
// 236.969 us; speedup vs baseline: 1.2328x; 1.2328x over previous
//
#include <hip/hip_runtime.h>
#include <hip/hip_bf16.h>
#include <cmath>

#define NB 4
#define NS 1024
#define ND 1024
#define NH 16
#define NDH 64
#define NKSP 32
#define SCALE 0.125f      // 1/sqrt(64)
#define LOG2E 1.44269504f
#define SCALE2 (SCALE * LOG2E)

typedef __attribute__((ext_vector_type(8))) short bf16x8;
typedef __attribute__((ext_vector_type(4))) float f32x4;
typedef unsigned long long u64;

#define AS1 __attribute__((address_space(1)))
#define AS3 __attribute__((address_space(3)))

__device__ __forceinline__ void gl_lds16(const void* g, void* l) {
    __builtin_amdgcn_global_load_lds((const AS1 void*)g, (AS3 void*)l, 16, 0, 0);
}

__device__ __forceinline__ ushort f2bf(float f) {
    union { __hip_bfloat16 h; ushort u; } cv;
    cv.h = __float2bfloat16(f);
    return cv.u;
}
__device__ __forceinline__ float bf2f(ushort u) {
    union { unsigned int i; float f; } cv;
    cv.i = ((unsigned int)u) << 16;
    return cv.f;
}
__device__ __forceinline__ float fexp2(float x) {
    return __builtin_amdgcn_exp2f(x);   // v_exp_f32 (base-2)
}

// ---------------------------------------------------------------------------
// y=0: x->bf16 (4096 blocks); y=1..4: W->bf16 (1024 blocks);
// y=5: pack pmask into bitwords (4096 blocks, one wave per u64 word).
// ---------------------------------------------------------------------------
__global__ __launch_bounds__(256)
void f2bf_multi(const float* __restrict__ x,
                const float* __restrict__ w0, const float* __restrict__ w1,
                const float* __restrict__ w2, const float* __restrict__ w3,
                const int* __restrict__ pm,
                ushort* __restrict__ xo,
                ushort* __restrict__ o0, ushort* __restrict__ o1,
                ushort* __restrict__ o2, ushort* __restrict__ o3,
                u64* __restrict__ bm)
{
    int y = blockIdx.y;
    if (y == 5) {
        int word = blockIdx.x * 4 + (threadIdx.x >> 6);
        int lane = threadIdx.x & 63;
        int row  = word >> 4, wcol = word & 15;
        int v = pm[(size_t)row * NS + wcol * 64 + lane];
        u64 b = __ballot(v != 0);
        if (lane == 0) bm[word] = b;
        return;
    }
    const float* src; ushort* dst; int nblk;
    if (y == 0)      { src = x;  dst = xo; nblk = 4096; }
    else if (y == 1) { src = w0; dst = o0; nblk = 1024; }
    else if (y == 2) { src = w1; dst = o1; nblk = 1024; }
    else if (y == 3) { src = w2; dst = o2; nblk = 1024; }
    else             { src = w3; dst = o3; nblk = 1024; }
    if (blockIdx.x >= (unsigned)nblk) return;
    int i = (blockIdx.x * 256 + threadIdx.x) * 4;
    float4 v = *(const float4*)&src[i];
    ushort4 o;
    o.x = f2bf(v.x); o.y = f2bf(v.y); o.z = f2bf(v.z); o.w = f2bf(v.w);
    *(ushort4*)&dst[i] = o;
}

// ---------------------------------------------------------------------------
// Fused QKV GEMM (direct-scatter epilogue; V also writes Vt).
// grid (24,32): blockIdx.x: [0,8)=Q [8,16)=K [16,24)=V.
// ---------------------------------------------------------------------------
__global__ __launch_bounds__(256)
void gemm_qkv(const ushort* __restrict__ xb,
              const ushort* __restrict__ Wqb, const ushort* __restrict__ Wkb,
              const ushort* __restrict__ Wvb,
              const float* __restrict__ bq, const float* __restrict__ bk,
              const float* __restrict__ bv,
              ushort* __restrict__ Qo, ushort* __restrict__ Ko,
              ushort* __restrict__ Vo, ushort* __restrict__ Vto)
{
    constexpr int K = ND;
    __shared__ __attribute__((aligned(16))) ushort As[128 * 32];
    __shared__ __attribute__((aligned(16))) ushort Bs[128 * 32];

    const int tid  = threadIdx.x;
    const int lane = tid & 63, w = tid >> 6;
    const int wm = w >> 1, wn = w & 1;
    const int which = blockIdx.x >> 3;
    const int n0 = (blockIdx.x & 7) * 128;
    const int m0 = blockIdx.y * 128;
    const int quad = lane >> 4, l16 = lane & 15;

    const ushort* W = (which == 0) ? Wqb : (which == 1) ? Wkb : Wvb;
    const float* bias = (which == 0) ? bq : (which == 1) ? bk : bv;
    ushort* Out = (which == 0) ? Qo : (which == 1) ? Ko : Vo;

    f32x4 acc[4][4] = {};

    for (int k0 = 0; k0 < K; k0 += 32) {
        __syncthreads();
#pragma unroll
        for (int u = 0; u < 2; ++u) {
            int t0 = u * 256 + w * 64;
            int t  = t0 + lane;
            int row = t >> 2, kc = (t & 3) * 8;
            gl_lds16(xb + (size_t)(m0 + row) * K + k0 + kc, &As[t0 * 8]);
            gl_lds16(W  + (size_t)(n0 + row) * K + k0 + kc, &Bs[t0 * 8]);
        }
        __syncthreads();

        bf16x8 af[4], bfr[4];
#pragma unroll
        for (int mt = 0; mt < 4; ++mt)
            af[mt] = *(const bf16x8*)&As[(wm*64 + mt*16 + l16) * 32 + quad*8];
#pragma unroll
        for (int nt = 0; nt < 4; ++nt)
            bfr[nt] = *(const bf16x8*)&Bs[(wn*64 + nt*16 + l16) * 32 + quad*8];
#pragma unroll
        for (int mt = 0; mt < 4; ++mt)
#pragma unroll
            for (int nt = 0; nt < 4; ++nt)
                acc[mt][nt] = __builtin_amdgcn_mfma_f32_16x16x32_bf16(
                    af[mt], bfr[nt], acc[mt][nt], 0, 0, 0);
    }

#pragma unroll
    for (int nt = 0; nt < 4; ++nt) {
        int n = n0 + wn*64 + nt*16 + l16;
        float bz = bias[n];
        int hh = n >> 6, dh = n & 63;
#pragma unroll
        for (int mt = 0; mt < 4; ++mt) {
#pragma unroll
            for (int rg = 0; rg < 4; ++rg) {
                int m = m0 + wm*64 + mt*16 + quad*4 + rg;
                int b = m >> 10, s = m & (NS - 1);
                ushort val = f2bf(acc[mt][nt][rg] + bz);
                Out[(((size_t)(b*NH + hh))*NS + s)*NDH + dh] = val;
                if (which == 2)
                    Vto[(((size_t)(b*NH + hh))*NDH + dh)*NS + s] = val;
            }
        }
    }
}

// ---------------------------------------------------------------------------
// Output GEMM: 64x128 tile -> 512 blocks.
// ---------------------------------------------------------------------------
__global__ __launch_bounds__(256)
void gemm_out(const ushort* __restrict__ A, const ushort* __restrict__ W,
              const float* __restrict__ bias, float* __restrict__ Cout)
{
    constexpr int K = ND;
    __shared__ __attribute__((aligned(16))) ushort As[64 * 32];
    __shared__ __attribute__((aligned(16))) ushort Bs[128 * 32];

    const int tid  = threadIdx.x;
    const int lane = tid & 63, w = tid >> 6;
    const int wm = w & 1, wn = w >> 1;
    const int m0 = blockIdx.y * 64, n0 = blockIdx.x * 128;
    const int quad = lane >> 4, l16 = lane & 15;

    f32x4 acc[2][4] = {};

    for (int k0 = 0; k0 < K; k0 += 32) {
        __syncthreads();
        {
            int t0 = w * 64;
            int t  = t0 + lane;
            int row = t >> 2, kc = (t & 3) * 8;
            gl_lds16(A + (size_t)(m0 + row) * K + k0 + kc, &As[t0 * 8]);
        }
#pragma unroll
        for (int u = 0; u < 2; ++u) {
            int t0 = u * 256 + w * 64;
            int t  = t0 + lane;
            int row = t >> 2, kc = (t & 3) * 8;
            gl_lds16(W + (size_t)(n0 + row) * K + k0 + kc, &Bs[t0 * 8]);
        }
        __syncthreads();

        bf16x8 af[2], bfr[4];
#pragma unroll
        for (int mt = 0; mt < 2; ++mt)
            af[mt] = *(const bf16x8*)&As[(wm*32 + mt*16 + l16) * 32 + quad*8];
#pragma unroll
        for (int nt = 0; nt < 4; ++nt)
            bfr[nt] = *(const bf16x8*)&Bs[(wn*64 + nt*16 + l16) * 32 + quad*8];
#pragma unroll
        for (int mt = 0; mt < 2; ++mt)
#pragma unroll
            for (int nt = 0; nt < 4; ++nt)
                acc[mt][nt] = __builtin_amdgcn_mfma_f32_16x16x32_bf16(
                    af[mt], bfr[nt], acc[mt][nt], 0, 0, 0);
    }

#pragma unroll
    for (int nt = 0; nt < 4; ++nt) {
        int n = n0 + wn*64 + nt*16 + l16;
        float bz = bias[n];
#pragma unroll
        for (int mt = 0; mt < 2; ++mt) {
#pragma unroll
            for (int rg = 0; rg < 4; ++rg) {
                int m = m0 + wm*32 + mt*16 + quad*4 + rg;
                Cout[(size_t)m * ND + n] = acc[mt][nt][rg] + bz;
            }
        }
    }
}

// ---------------------------------------------------------------------------
// MFMA flash attention — round-0 geometry (256 thr / 4 waves / 128 q-rows /
// grid 512; <=2 blocks/CU so <=2 heads -> 32KB K/V stays L1-resident),
// plus two targeted fixes:
//  (1) Register double-buffer of BOTH kf and vf for kt+1, issued before
//      STEP(kt)'s ~800cy compute chain. r0 counters (issue-busy 22%) say
//      exposed load latency dominates; r2 proved the idea but strangled it
//      at 64 VGPRs (spill: WRITE_SIZE 8->61MB). Here: ~220 VGPR, within
//      the 256/wave budget at 2 waves/SIMD -> __launch_bounds__(256,2).
//      Buffers statically named A/B, loop unrolled x2 (no runtime idx).
//  (2) MW re-laid as [kt][row]: r0's MW[qrow*16+kt] ds_read_b64 was a
//      16-way bank conflict (1.57M conflict cycles); [kt][row] makes the
//      read conflict-free (lanes 0-15 consecutive u64, quads broadcast).
//      One-time conflicted staging write is noise.
// Dense math unchanged from r0: S^T mfma(kf,qf); base-2 exp; lsum via
// ones-MFMA; no max subtraction (scores bounded). Sparse path unchanged.
// LDS = Ps 18432 + MW 16384 = 34.8 KB.
// ---------------------------------------------------------------------------
#define LOADK(DST, KT)                                                        \
    _Pragma("unroll")                                                         \
    for (int nt = 0; nt < 4; ++nt)                                            \
        _Pragma("unroll")                                                     \
        for (int kk = 0; kk < 2; ++kk)                                        \
            DST[nt][kk] = *(const bf16x8*)                                    \
                &Kh[(size_t)((KT)*64 + nt*16 + l16) * NDH + kk*32 + quad*8];

#define LOADV(DST, KT)                                                        \
    _Pragma("unroll")                                                         \
    for (int nt = 0; nt < 4; ++nt)                                            \
        _Pragma("unroll")                                                     \
        for (int kk = 0; kk < 2; ++kk)                                        \
            DST[nt][kk] = *(const bf16x8*)                                    \
                &Vth[(size_t)(nt*16 + l16) * NS + (KT)*64 + kk*32 + quad*8];

// One K-tile step: both qh halves, using fragment buffers KF/VF.
#define STEP(KT, KF, VF)                                                      \
    _Pragma("unroll")                                                         \
    for (int qh = 0; qh < 2; ++qh) {                                          \
        const int qrow = w*32 + qh*16 + l16;                                  \
        u64 wq = MW[(KT)*128 + qrow] >> (quad * 4);                           \
        f32x4 s_acc[4] = {};                                                  \
        __builtin_amdgcn_s_setprio(1);                                        \
        _Pragma("unroll")                                                     \
        for (int nt = 0; nt < 4; ++nt)                                        \
            _Pragma("unroll")                                                 \
            for (int kk = 0; kk < 2; ++kk)                                    \
                s_acc[nt] = __builtin_amdgcn_mfma_f32_16x16x32_bf16(          \
                    KF[nt][kk], qf[qh][kk], s_acc[nt], 0, 0, 0);              \
        __builtin_amdgcn_s_setprio(0);                                        \
        _Pragma("unroll")                                                     \
        for (int nt = 0; nt < 4; ++nt) {                                      \
            ushort4 pk;                                                       \
            float p0 = fexp2(fmaf(s_acc[nt][0], SCALE2,                       \
                 ((wq >> (nt*16 + 0)) & 1ULL) ? 0.f : nlam2));                \
            float p1 = fexp2(fmaf(s_acc[nt][1], SCALE2,                       \
                 ((wq >> (nt*16 + 1)) & 1ULL) ? 0.f : nlam2));                \
            float p2 = fexp2(fmaf(s_acc[nt][2], SCALE2,                       \
                 ((wq >> (nt*16 + 2)) & 1ULL) ? 0.f : nlam2));                \
            float p3 = fexp2(fmaf(s_acc[nt][3], SCALE2,                       \
                 ((wq >> (nt*16 + 3)) & 1ULL) ? 0.f : nlam2));                \
            pk.x = f2bf(p0); pk.y = f2bf(p1);                                 \
            pk.z = f2bf(p2); pk.w = f2bf(p3);                                 \
            *(ushort4*)&Ps[qrow*72 + nt*16 + quad*4] = pk;                    \
        }                                                                     \
        bf16x8 pf[2];                                                         \
        _Pragma("unroll")                                                     \
        for (int kk = 0; kk < 2; ++kk)                                        \
            pf[kk] = *(const bf16x8*)&Ps[qrow*72 + kk*32 + quad*8];           \
        __builtin_amdgcn_s_setprio(1);                                        \
        _Pragma("unroll")                                                     \
        for (int kk = 0; kk < 2; ++kk) {                                      \
            l_acc[qh] = __builtin_amdgcn_mfma_f32_16x16x32_bf16(              \
                pf[kk], ones.v, l_acc[qh], 0, 0, 0);                          \
            _Pragma("unroll")                                                 \
            for (int nt = 0; nt < 4; ++nt)                                    \
                o_acc[qh][nt] = __builtin_amdgcn_mfma_f32_16x16x32_bf16(      \
                    pf[kk], VF[nt][kk], o_acc[qh][nt], 0, 0, 0);              \
        }                                                                     \
        __builtin_amdgcn_s_setprio(0);                                        \
    }

__global__ __launch_bounds__(256, 2)
void attn_kernel(const ushort* __restrict__ Qb, const ushort* __restrict__ Kb,
                 const ushort* __restrict__ Vb, const ushort* __restrict__ Vt,
                 const u64* __restrict__ bm,
                 const int* __restrict__ pidx, const int* __restrict__ pimask,
                 const float* __restrict__ u_prev, ushort* __restrict__ OA)
{
    __shared__ __attribute__((aligned(16))) ushort Ps[128 * 72];
    __shared__ __attribute__((aligned(16))) u64    MW[16 * 128];

    const int tid  = threadIdx.x;
    const int lane = tid & 63, w = tid >> 6;
    const int quad = lane >> 4, l16 = lane & 15;

    const int id    = blockIdx.x;
    const int xcd   = id & 7;
    const int t5    = id >> 3;            // 0..63
    const int qtile = t5 & 7;
    const int head  = (t5 >> 3) * 8 + xcd;
    const int b = head >> 4, h = head & 15;
    const int s0 = qtile * 128;

    const float lam = 10.0f * __expf(-5.0f * u_prev[b]);
    const bool sparse = (lam >= 1.0f);

    const size_t bh = (size_t)b * NH + h;
    const ushort* Qh  = Qb + bh * NS * NDH;
    const ushort* Kh  = Kb + bh * NS * NDH;
    const ushort* Vh  = Vb + bh * NS * NDH;
    const ushort* Vth = Vt + bh * NDH * NS;

    if (!sparse) {
        const float nlam2 = -lam * LOG2E;   // base-2 bias

        // stage mask words as MW[kt][row] (16 KB): coalesced global read;
        // the (one-time) conflicted LDS write is noise.
#pragma unroll
        for (int u = 0; u < 8; ++u) {
            int idx = u * 256 + tid;              // 0..2047
            int row = idx >> 4, wd = idx & 15;
            MW[wd * 128 + row] = bm[(size_t)s0 * 16 + idx];
        }
        __syncthreads();   // the only block barrier

        // Q fragments (serve as B-operand = Q^T)
        bf16x8 qf[2][2];
#pragma unroll
        for (int qh = 0; qh < 2; ++qh)
#pragma unroll
            for (int kk = 0; kk < 2; ++kk)
                qf[qh][kk] = *(const bf16x8*)
                    &Qh[(size_t)(s0 + w*32 + qh*16 + l16) * NDH + kk*32 + quad*8];

        union { bf16x8 v; ushort s[8]; } ones;
#pragma unroll
        for (int i = 0; i < 8; ++i) ones.s[i] = 0x3F80;  // bf16 1.0

        f32x4 o_acc[2][4] = {};
        f32x4 l_acc[2] = {};

        // register-double-buffered K and V fragments (A=even kt, B=odd kt)
        bf16x8 kfA[4][2], vfA[4][2], kfB[4][2], vfB[4][2];
        LOADK(kfA, 0);
        LOADV(vfA, 0);

        for (int kt = 0; kt < 16; kt += 2) {
            // issue kt+1's loads before computing kt
            LOADK(kfB, kt + 1);
            LOADV(vfB, kt + 1);
            STEP(kt, kfA, vfA);

            // issue kt+2's loads before computing kt+1
            if (kt + 2 < 16) {
                LOADK(kfA, kt + 2);
                LOADV(vfA, kt + 2);
            }
            STEP(kt + 1, kfB, vfB);
        }

        // epilogue (o_acc: row=query quad*4+rg, col=dh nt*16+l16)
#pragma unroll
        for (int qh = 0; qh < 2; ++qh) {
            float inv[4];
#pragma unroll
            for (int rg = 0; rg < 4; ++rg) inv[rg] = 1.f / l_acc[qh][rg];
#pragma unroll
            for (int nt = 0; nt < 4; ++nt)
#pragma unroll
                for (int rg = 0; rg < 4; ++rg) {
                    int m = w*32 + qh*16 + quad*4 + rg;
                    OA[((size_t)b*NS + s0 + m)*ND + h*NDH + nt*16 + l16] =
                        f2bf(o_acc[qh][nt][rg] * inv[rg]);
                }
        }
    } else {
        // ---------------- sparse path (fp32 scalar, bf16 inputs) ----------
        const int r2  = lane & 15;
        const int cg  = lane >> 4;
#pragma unroll
        for (int qh = 0; qh < 2; ++qh) {
            const int row = w*32 + qh*16 + r2;

            float qreg[64];
            {
                const ushort* qp = Qh + (size_t)(s0 + row) * NDH;
#pragma unroll
                for (int c = 0; c < 8; ++c) {
                    union { bf16x8 v; ushort s[8]; } qv;
                    qv.v = *(const bf16x8*)(qp + c*8);
#pragma unroll
                    for (int j = 0; j < 8; ++j) qreg[c*8 + j] = bf2f(qv.s[j]);
                }
            }

            float sc[8];
#pragma unroll
            for (int jj = 0; jj < 8; ++jj) {
                int j  = cg*8 + jj;
                int mv = pimask[(size_t)(s0+row)*NKSP + j];
                if (mv) {
                    int kv = pidx[(size_t)(s0+row)*NKSP + j];
                    const ushort* krow = &Kh[(size_t)kv * NDH];
                    float acc = 0.f;
#pragma unroll
                    for (int c = 0; c < 8; ++c) {
                        union { bf16x8 v; ushort s[8]; } kk;
                        kk.v = *(const bf16x8*)(krow + c*8);
#pragma unroll
                        for (int jb = 0; jb < 8; ++jb)
                            acc = fmaf(qreg[c*8 + jb], bf2f(kk.s[jb]), acc);
                    }
                    sc[jj] = acc * SCALE;
                } else {
                    sc[jj] = -INFINITY;
                }
            }
            float mt = sc[0];
#pragma unroll
            for (int jj = 1; jj < 8; ++jj) mt = fmaxf(mt, sc[jj]);
            mt = fmaxf(mt, __shfl_xor(mt, 16));
            mt = fmaxf(mt, __shfl_xor(mt, 32));

            float psum = 0.f;
#pragma unroll
            for (int jj = 0; jj < 8; ++jj) {
                float p = __expf(sc[jj] - mt);
                psum += p;
                Ps[row * 72 + cg*8 + jj] = f2bf(p);
            }
            psum += __shfl_xor(psum, 16);
            psum += __shfl_xor(psum, 32);

            float o[16];
#pragma unroll
            for (int i = 0; i < 16; ++i) o[i] = 0.f;

            for (int j = 0; j < 32; ++j) {
                float p = bf2f(Ps[row * 72 + j]);
                if (p != 0.f) {
                    int kv = pidx[(size_t)(s0+row)*NKSP + j];
                    const ushort* vrow = &Vh[(size_t)kv * NDH + cg*16];
#pragma unroll
                    for (int c = 0; c < 2; ++c) {
                        union { bf16x8 v; ushort s[8]; } vv;
                        vv.v = *(const bf16x8*)(vrow + c*8);
#pragma unroll
                        for (int jb = 0; jb < 8; ++jb)
                            o[c*8 + jb] = fmaf(p, bf2f(vv.s[jb]), o[c*8 + jb]);
                    }
                }
            }

            float inv = 1.f / psum;
            ushort* op = OA + ((size_t)b*NS + s0 + row)*ND + h*NDH + cg*16;
#pragma unroll
            for (int i4 = 0; i4 < 4; ++i4) {
                ushort4 v;
                v.x = f2bf(o[i4*4+0]*inv); v.y = f2bf(o[i4*4+1]*inv);
                v.z = f2bf(o[i4*4+2]*inv); v.w = f2bf(o[i4*4+3]*inv);
                *(ushort4*)(op + i4*4) = v;
            }
        }
    }
}

// ---------------------------------------------------------------------------
extern "C" void kernel_launch(void* const* d_in, const int* in_sizes, int n_in,
                              void* d_out, int out_size, void* d_ws, size_t ws_size,
                              hipStream_t stream)
{
    const float* x      = (const float*)d_in[0];
    const int*   pmask  = (const int*)  d_in[1];
    const int*   pidx   = (const int*)  d_in[2];
    const int*   pimask = (const int*)  d_in[3];
    const float* u_prev = (const float*)d_in[4];
    const float* Wq     = (const float*)d_in[5];
    const float* bq     = (const float*)d_in[6];
    const float* Wk     = (const float*)d_in[7];
    const float* bk     = (const float*)d_in[8];
    const float* Wv     = (const float*)d_in[9];
    const float* bv     = (const float*)d_in[10];
    const float* Wo     = (const float*)d_in[11];
    const float* bo     = (const float*)d_in[12];
    float* out = (float*)d_out;

    const size_t QSZ = (size_t)NB * NH * NS * NDH;   // 4,194,304 elements
    const size_t WSZ = (size_t)ND * ND;              // 1,048,576 elements
    ushort* xb  = (ushort*)d_ws;        // bf16 x              (8 MB)
    ushort* Qw  = xb  + QSZ;            // bf16 Q (b,h,s,dh)   (8 MB)
    ushort* Kw  = Qw  + QSZ;            // bf16 K              (8 MB)
    ushort* Vw  = Kw  + QSZ;            // bf16 V              (8 MB)
    ushort* Vtw = Vw  + QSZ;            // bf16 V^T (b,h,dh,s) (8 MB)
    ushort* Awb = Vtw + QSZ;            // bf16 attn out       (8 MB)
    ushort* Wqb = Awb + QSZ;            // bf16 weights (2 MB each)
    ushort* Wkb = Wqb + WSZ;
    ushort* Wvb = Wkb + WSZ;
    ushort* Wob = Wvb + WSZ;
    u64*    bmw = (u64*)(Wob + WSZ);    // packed mask (128 KB)

    f2bf_multi<<<dim3(4096, 6), 256, 0, stream>>>(
        x, Wq, Wk, Wv, Wo, pmask, xb, Wqb, Wkb, Wvb, Wob, bmw);

    gemm_qkv<<<dim3(24, 32), 256, 0, stream>>>(
        xb, Wqb, Wkb, Wvb, bq, bk, bv, Qw, Kw, Vw, Vtw);

    attn_kernel<<<512, 256, 0, stream>>>(
        Qw, Kw, Vw, Vtw, bmw, pidx, pimask, u_prev, Awb);

    gemm_out<<<dim3(ND/128, (NB*NS)/64), 256, 0, stream>>>(Awb, Wob, bo, out);
}

// Round 4
// 236.415 us; speedup vs baseline: 1.2357x; 1.0023x over previous
//
#include <hip/hip_runtime.h>
#include <hip/hip_bf16.h>
#include <cmath>

#define NB 4
#define NS 1024
#define ND 1024
#define NH 16
#define NDH 64
#define NKSP 32
#define SCALE 0.125f      // 1/sqrt(64)
#define LOG2E 1.44269504f
#define SCALE2 (SCALE * LOG2E)

typedef __attribute__((ext_vector_type(8))) short bf16x8;
typedef __attribute__((ext_vector_type(4))) float f32x4;
typedef unsigned long long u64;

#define AS1 __attribute__((address_space(1)))
#define AS3 __attribute__((address_space(3)))

__device__ __forceinline__ void gl_lds16(const void* g, void* l) {
    __builtin_amdgcn_global_load_lds((const AS1 void*)g, (AS3 void*)l, 16, 0, 0);
}

__device__ __forceinline__ ushort f2bf(float f) {
    union { __hip_bfloat16 h; ushort u; } cv;
    cv.h = __float2bfloat16(f);
    return cv.u;
}
__device__ __forceinline__ float bf2f(ushort u) {
    union { unsigned int i; float f; } cv;
    cv.i = ((unsigned int)u) << 16;
    return cv.f;
}
__device__ __forceinline__ float fexp2(float x) {
    return __builtin_amdgcn_exp2f(x);   // v_exp_f32 (base-2)
}

// ---------------------------------------------------------------------------
// y=0: x->bf16 (4096 blocks); y=1..4: W->bf16 (1024 blocks);
// y=5: pack pmask into bitwords (4096 blocks, one wave per u64 word).
// ---------------------------------------------------------------------------
__global__ __launch_bounds__(256)
void f2bf_multi(const float* __restrict__ x,
                const float* __restrict__ w0, const float* __restrict__ w1,
                const float* __restrict__ w2, const float* __restrict__ w3,
                const int* __restrict__ pm,
                ushort* __restrict__ xo,
                ushort* __restrict__ o0, ushort* __restrict__ o1,
                ushort* __restrict__ o2, ushort* __restrict__ o3,
                u64* __restrict__ bm)
{
    int y = blockIdx.y;
    if (y == 5) {
        int word = blockIdx.x * 4 + (threadIdx.x >> 6);
        int lane = threadIdx.x & 63;
        int row  = word >> 4, wcol = word & 15;
        int v = pm[(size_t)row * NS + wcol * 64 + lane];
        u64 b = __ballot(v != 0);
        if (lane == 0) bm[word] = b;
        return;
    }
    const float* src; ushort* dst; int nblk;
    if (y == 0)      { src = x;  dst = xo; nblk = 4096; }
    else if (y == 1) { src = w0; dst = o0; nblk = 1024; }
    else if (y == 2) { src = w1; dst = o1; nblk = 1024; }
    else if (y == 3) { src = w2; dst = o2; nblk = 1024; }
    else             { src = w3; dst = o3; nblk = 1024; }
    if (blockIdx.x >= (unsigned)nblk) return;
    int i = (blockIdx.x * 256 + threadIdx.x) * 4;
    float4 v = *(const float4*)&src[i];
    ushort4 o;
    o.x = f2bf(v.x); o.y = f2bf(v.y); o.z = f2bf(v.z); o.w = f2bf(v.w);
    *(ushort4*)&dst[i] = o;
}

// ---------------------------------------------------------------------------
// Fused QKV GEMM (direct-scatter epilogue; V also writes Vt).
// grid (24,32): blockIdx.x: [0,8)=Q [8,16)=K [16,24)=V.
// ---------------------------------------------------------------------------
__global__ __launch_bounds__(256)
void gemm_qkv(const ushort* __restrict__ xb,
              const ushort* __restrict__ Wqb, const ushort* __restrict__ Wkb,
              const ushort* __restrict__ Wvb,
              const float* __restrict__ bq, const float* __restrict__ bk,
              const float* __restrict__ bv,
              ushort* __restrict__ Qo, ushort* __restrict__ Ko,
              ushort* __restrict__ Vo, ushort* __restrict__ Vto)
{
    constexpr int K = ND;
    __shared__ __attribute__((aligned(16))) ushort As[128 * 32];
    __shared__ __attribute__((aligned(16))) ushort Bs[128 * 32];

    const int tid  = threadIdx.x;
    const int lane = tid & 63, w = tid >> 6;
    const int wm = w >> 1, wn = w & 1;
    const int which = blockIdx.x >> 3;
    const int n0 = (blockIdx.x & 7) * 128;
    const int m0 = blockIdx.y * 128;
    const int quad = lane >> 4, l16 = lane & 15;

    const ushort* W = (which == 0) ? Wqb : (which == 1) ? Wkb : Wvb;
    const float* bias = (which == 0) ? bq : (which == 1) ? bk : bv;
    ushort* Out = (which == 0) ? Qo : (which == 1) ? Ko : Vo;

    f32x4 acc[4][4] = {};

    for (int k0 = 0; k0 < K; k0 += 32) {
        __syncthreads();
#pragma unroll
        for (int u = 0; u < 2; ++u) {
            int t0 = u * 256 + w * 64;
            int t  = t0 + lane;
            int row = t >> 2, kc = (t & 3) * 8;
            gl_lds16(xb + (size_t)(m0 + row) * K + k0 + kc, &As[t0 * 8]);
            gl_lds16(W  + (size_t)(n0 + row) * K + k0 + kc, &Bs[t0 * 8]);
        }
        __syncthreads();

        bf16x8 af[4], bfr[4];
#pragma unroll
        for (int mt = 0; mt < 4; ++mt)
            af[mt] = *(const bf16x8*)&As[(wm*64 + mt*16 + l16) * 32 + quad*8];
#pragma unroll
        for (int nt = 0; nt < 4; ++nt)
            bfr[nt] = *(const bf16x8*)&Bs[(wn*64 + nt*16 + l16) * 32 + quad*8];
#pragma unroll
        for (int mt = 0; mt < 4; ++mt)
#pragma unroll
            for (int nt = 0; nt < 4; ++nt)
                acc[mt][nt] = __builtin_amdgcn_mfma_f32_16x16x32_bf16(
                    af[mt], bfr[nt], acc[mt][nt], 0, 0, 0);
    }

#pragma unroll
    for (int nt = 0; nt < 4; ++nt) {
        int n = n0 + wn*64 + nt*16 + l16;
        float bz = bias[n];
        int hh = n >> 6, dh = n & 63;
#pragma unroll
        for (int mt = 0; mt < 4; ++mt) {
#pragma unroll
            for (int rg = 0; rg < 4; ++rg) {
                int m = m0 + wm*64 + mt*16 + quad*4 + rg;
                int b = m >> 10, s = m & (NS - 1);
                ushort val = f2bf(acc[mt][nt][rg] + bz);
                Out[(((size_t)(b*NH + hh))*NS + s)*NDH + dh] = val;
                if (which == 2)
                    Vto[(((size_t)(b*NH + hh))*NDH + dh)*NS + s] = val;
            }
        }
    }
}

// ---------------------------------------------------------------------------
// Output GEMM: 64x128 tile -> 512 blocks.
// ---------------------------------------------------------------------------
__global__ __launch_bounds__(256)
void gemm_out(const ushort* __restrict__ A, const ushort* __restrict__ W,
              const float* __restrict__ bias, float* __restrict__ Cout)
{
    constexpr int K = ND;
    __shared__ __attribute__((aligned(16))) ushort As[64 * 32];
    __shared__ __attribute__((aligned(16))) ushort Bs[128 * 32];

    const int tid  = threadIdx.x;
    const int lane = tid & 63, w = tid >> 6;
    const int wm = w & 1, wn = w >> 1;
    const int m0 = blockIdx.y * 64, n0 = blockIdx.x * 128;
    const int quad = lane >> 4, l16 = lane & 15;

    f32x4 acc[2][4] = {};

    for (int k0 = 0; k0 < K; k0 += 32) {
        __syncthreads();
        {
            int t0 = w * 64;
            int t  = t0 + lane;
            int row = t >> 2, kc = (t & 3) * 8;
            gl_lds16(A + (size_t)(m0 + row) * K + k0 + kc, &As[t0 * 8]);
        }
#pragma unroll
        for (int u = 0; u < 2; ++u) {
            int t0 = u * 256 + w * 64;
            int t  = t0 + lane;
            int row = t >> 2, kc = (t & 3) * 8;
            gl_lds16(W + (size_t)(n0 + row) * K + k0 + kc, &Bs[t0 * 8]);
        }
        __syncthreads();

        bf16x8 af[2], bfr[4];
#pragma unroll
        for (int mt = 0; mt < 2; ++mt)
            af[mt] = *(const bf16x8*)&As[(wm*32 + mt*16 + l16) * 32 + quad*8];
#pragma unroll
        for (int nt = 0; nt < 4; ++nt)
            bfr[nt] = *(const bf16x8*)&Bs[(wn*64 + nt*16 + l16) * 32 + quad*8];
#pragma unroll
        for (int mt = 0; mt < 2; ++mt)
#pragma unroll
            for (int nt = 0; nt < 4; ++nt)
                acc[mt][nt] = __builtin_amdgcn_mfma_f32_16x16x32_bf16(
                    af[mt], bfr[nt], acc[mt][nt], 0, 0, 0);
    }

#pragma unroll
    for (int nt = 0; nt < 4; ++nt) {
        int n = n0 + wn*64 + nt*16 + l16;
        float bz = bias[n];
#pragma unroll
        for (int mt = 0; mt < 2; ++mt) {
#pragma unroll
            for (int rg = 0; rg < 4; ++rg) {
                int m = m0 + wm*32 + mt*16 + quad*4 + rg;
                Cout[(size_t)m * ND + n] = acc[mt][nt][rg] + bz;
            }
        }
    }
}

// ---------------------------------------------------------------------------
// MFMA flash attention — round-0 geometry (256 thr / 4 waves / 128 q-rows /
// grid 512) with the K/V feed moved to a 2-phase LDS pipeline.
// Post-mortem r3: compiler SANK the register prefetches (VGPR 116 = r0,
// dur identical) — plain loads can't be pipelined at source level. Fix:
// global_load_lds is fire-and-forget (no dest VGPR, tracked by vmcnt) so
// the compiler cannot sink it. Per kt: stage K+V tile (16KB) for kt+1 via
// 4 gl_lds16/wave -> ds_read_b128 fragments of tile kt -> MFMA/exp ->
// one __syncthreads (its vmcnt drain is covered by the ~700cy compute).
// Swizzle (rule #21, both-sides-or-neither): LDS dest linear; global
// SOURCE chunk pre-swizzled sub^=(row&7) (16B chunks, alignment and
// line-coalescing preserved); READ uses chunk=(kk*4+quad)^(l16&7).
// Per-load bank coverage: 16 rows x 4 chunks = 1KB spread evenly over
// all 32 banks (8 words/bank = ds_read_b128 floor) -> conflict-free.
// MW stays [kt][row] (conflict-free read). Dense math unchanged:
// S^T mfma(kf,qf); base-2 exp; lsum via ones-MFMA; no max subtraction.
// LDS = Ps 18432 + MW 16384 + KV 32768 = 67.6 KB -> 2 blocks/CU.
// ---------------------------------------------------------------------------

// Stage K-tile (chunks 0..511) + V-tile (512..1023) for K-tile KT into
// KV[BUF]. Wave w covers chunks [w*256, w*256+256) in 4 gl_lds calls.
// LDS chunk c holds global chunk (row, sub ^ (row&7)) — source-swizzled.
#define STAGE(BUF, KT)                                                        \
    _Pragma("unroll")                                                         \
    for (int u = 0; u < 4; ++u) {                                             \
        int cb = w * 256 + u * 64;                                            \
        int c  = cb + lane;                                                   \
        const ushort* src;                                                    \
        if (w < 2) {                                                          \
            int row = c >> 3, sub = c & 7;                                    \
            src = Kh + (((size_t)((KT)*64 + row)) << 6)                       \
                     + ((sub ^ (row & 7)) << 3);                              \
        } else {                                                              \
            int c2 = c - 512;                                                 \
            int row = c2 >> 3, sub = c2 & 7;                                  \
            src = Vth + (size_t)row * NS + (KT)*64                            \
                      + ((sub ^ (row & 7)) << 3);                             \
        }                                                                     \
        gl_lds16(src, (ushort*)&KV[BUF][0][0] + (size_t)cb * 8);              \
    }

// Read fragments of tile BUF (swizzled chunk index).
#define LOADKV(KF, VF, BUF)                                                   \
    _Pragma("unroll")                                                         \
    for (int nt = 0; nt < 4; ++nt)                                            \
        _Pragma("unroll")                                                     \
        for (int kk = 0; kk < 2; ++kk) {                                      \
            int rowk = nt*16 + l16;                                           \
            int ck = (kk*4 + quad) ^ (l16 & 7);                               \
            KF[nt][kk] = *(const bf16x8*)&KV[BUF][0][rowk*64 + ck*8];         \
            VF[nt][kk] = *(const bf16x8*)&KV[BUF][1][rowk*64 + ck*8];         \
        }

// One K-tile step: both qh halves, using fragment buffers KF/VF.
#define STEP(KT, KF, VF)                                                      \
    _Pragma("unroll")                                                         \
    for (int qh = 0; qh < 2; ++qh) {                                          \
        const int qrow = w*32 + qh*16 + l16;                                  \
        u64 wq = MW[(KT)*128 + qrow] >> (quad * 4);                           \
        f32x4 s_acc[4] = {};                                                  \
        __builtin_amdgcn_s_setprio(1);                                        \
        _Pragma("unroll")                                                     \
        for (int nt = 0; nt < 4; ++nt)                                        \
            _Pragma("unroll")                                                 \
            for (int kk = 0; kk < 2; ++kk)                                    \
                s_acc[nt] = __builtin_amdgcn_mfma_f32_16x16x32_bf16(          \
                    KF[nt][kk], qf[qh][kk], s_acc[nt], 0, 0, 0);              \
        __builtin_amdgcn_s_setprio(0);                                        \
        _Pragma("unroll")                                                     \
        for (int nt = 0; nt < 4; ++nt) {                                      \
            ushort4 pk;                                                       \
            float p0 = fexp2(fmaf(s_acc[nt][0], SCALE2,                       \
                 ((wq >> (nt*16 + 0)) & 1ULL) ? 0.f : nlam2));                \
            float p1 = fexp2(fmaf(s_acc[nt][1], SCALE2,                       \
                 ((wq >> (nt*16 + 1)) & 1ULL) ? 0.f : nlam2));                \
            float p2 = fexp2(fmaf(s_acc[nt][2], SCALE2,                       \
                 ((wq >> (nt*16 + 2)) & 1ULL) ? 0.f : nlam2));                \
            float p3 = fexp2(fmaf(s_acc[nt][3], SCALE2,                       \
                 ((wq >> (nt*16 + 3)) & 1ULL) ? 0.f : nlam2));                \
            pk.x = f2bf(p0); pk.y = f2bf(p1);                                 \
            pk.z = f2bf(p2); pk.w = f2bf(p3);                                 \
            *(ushort4*)&Ps[qrow*72 + nt*16 + quad*4] = pk;                    \
        }                                                                     \
        bf16x8 pf[2];                                                         \
        _Pragma("unroll")                                                     \
        for (int kk = 0; kk < 2; ++kk)                                        \
            pf[kk] = *(const bf16x8*)&Ps[qrow*72 + kk*32 + quad*8];           \
        __builtin_amdgcn_s_setprio(1);                                        \
        _Pragma("unroll")                                                     \
        for (int kk = 0; kk < 2; ++kk) {                                      \
            l_acc[qh] = __builtin_amdgcn_mfma_f32_16x16x32_bf16(              \
                pf[kk], ones.v, l_acc[qh], 0, 0, 0);                          \
            _Pragma("unroll")                                                 \
            for (int nt = 0; nt < 4; ++nt)                                    \
                o_acc[qh][nt] = __builtin_amdgcn_mfma_f32_16x16x32_bf16(      \
                    pf[kk], VF[nt][kk], o_acc[qh][nt], 0, 0, 0);              \
        }                                                                     \
        __builtin_amdgcn_s_setprio(0);                                        \
    }

__global__ __launch_bounds__(256, 2)
void attn_kernel(const ushort* __restrict__ Qb, const ushort* __restrict__ Kb,
                 const ushort* __restrict__ Vb, const ushort* __restrict__ Vt,
                 const u64* __restrict__ bm,
                 const int* __restrict__ pidx, const int* __restrict__ pimask,
                 const float* __restrict__ u_prev, ushort* __restrict__ OA)
{
    __shared__ __attribute__((aligned(16))) ushort Ps[128 * 72];
    __shared__ __attribute__((aligned(16))) u64    MW[16 * 128];
    __shared__ __attribute__((aligned(16))) ushort KV[2][2][64 * 64];

    const int tid  = threadIdx.x;
    const int lane = tid & 63, w = tid >> 6;
    const int quad = lane >> 4, l16 = lane & 15;

    const int id    = blockIdx.x;
    const int xcd   = id & 7;
    const int t5    = id >> 3;            // 0..63
    const int qtile = t5 & 7;
    const int head  = (t5 >> 3) * 8 + xcd;
    const int b = head >> 4, h = head & 15;
    const int s0 = qtile * 128;

    const float lam = 10.0f * __expf(-5.0f * u_prev[b]);
    const bool sparse = (lam >= 1.0f);

    const size_t bh = (size_t)b * NH + h;
    const ushort* Qh  = Qb + bh * NS * NDH;
    const ushort* Kh  = Kb + bh * NS * NDH;
    const ushort* Vh  = Vb + bh * NS * NDH;
    const ushort* Vth = Vt + bh * NDH * NS;

    if (!sparse) {
        const float nlam2 = -lam * LOG2E;   // base-2 bias

        // stage tile 0 (fire-and-forget) + mask words MW[kt][row]
        STAGE(0, 0);
#pragma unroll
        for (int u = 0; u < 8; ++u) {
            int idx = u * 256 + tid;              // 0..2047
            int row = idx >> 4, wd = idx & 15;
            MW[wd * 128 + row] = bm[(size_t)s0 * 16 + idx];
        }

        // Q fragments (serve as B-operand = Q^T)
        bf16x8 qf[2][2];
#pragma unroll
        for (int qh = 0; qh < 2; ++qh)
#pragma unroll
            for (int kk = 0; kk < 2; ++kk)
                qf[qh][kk] = *(const bf16x8*)
                    &Qh[(size_t)(s0 + w*32 + qh*16 + l16) * NDH + kk*32 + quad*8];

        union { bf16x8 v; ushort s[8]; } ones;
#pragma unroll
        for (int i = 0; i < 8; ++i) ones.s[i] = 0x3F80;  // bf16 1.0

        f32x4 o_acc[2][4] = {};
        f32x4 l_acc[2] = {};

        __syncthreads();   // tile 0 + MW visible

        int cur = 0;
        for (int kt = 0; kt < 16; ++kt) {
            if (kt + 1 < 16) STAGE(cur ^ 1, kt + 1);
            bf16x8 kf[4][2], vf[4][2];
            LOADKV(kf, vf, cur);
            STEP(kt, kf, vf);
            __syncthreads();   // drains stage(kt+1); protects buf reuse
            cur ^= 1;
        }

        // epilogue (o_acc: row=query quad*4+rg, col=dh nt*16+l16)
#pragma unroll
        for (int qh = 0; qh < 2; ++qh) {
            float inv[4];
#pragma unroll
            for (int rg = 0; rg < 4; ++rg) inv[rg] = 1.f / l_acc[qh][rg];
#pragma unroll
            for (int nt = 0; nt < 4; ++nt)
#pragma unroll
                for (int rg = 0; rg < 4; ++rg) {
                    int m = w*32 + qh*16 + quad*4 + rg;
                    OA[((size_t)b*NS + s0 + m)*ND + h*NDH + nt*16 + l16] =
                        f2bf(o_acc[qh][nt][rg] * inv[rg]);
                }
        }
    } else {
        // ---------------- sparse path (fp32 scalar, bf16 inputs) ----------
        const int r2  = lane & 15;
        const int cg  = lane >> 4;
#pragma unroll
        for (int qh = 0; qh < 2; ++qh) {
            const int row = w*32 + qh*16 + r2;

            float qreg[64];
            {
                const ushort* qp = Qh + (size_t)(s0 + row) * NDH;
#pragma unroll
                for (int c = 0; c < 8; ++c) {
                    union { bf16x8 v; ushort s[8]; } qv;
                    qv.v = *(const bf16x8*)(qp + c*8);
#pragma unroll
                    for (int j = 0; j < 8; ++j) qreg[c*8 + j] = bf2f(qv.s[j]);
                }
            }

            float sc[8];
#pragma unroll
            for (int jj = 0; jj < 8; ++jj) {
                int j  = cg*8 + jj;
                int mv = pimask[(size_t)(s0+row)*NKSP + j];
                if (mv) {
                    int kv = pidx[(size_t)(s0+row)*NKSP + j];
                    const ushort* krow = &Kh[(size_t)kv * NDH];
                    float acc = 0.f;
#pragma unroll
                    for (int c = 0; c < 8; ++c) {
                        union { bf16x8 v; ushort s[8]; } kk;
                        kk.v = *(const bf16x8*)(krow + c*8);
#pragma unroll
                        for (int jb = 0; jb < 8; ++jb)
                            acc = fmaf(qreg[c*8 + jb], bf2f(kk.s[jb]), acc);
                    }
                    sc[jj] = acc * SCALE;
                } else {
                    sc[jj] = -INFINITY;
                }
            }
            float mt = sc[0];
#pragma unroll
            for (int jj = 1; jj < 8; ++jj) mt = fmaxf(mt, sc[jj]);
            mt = fmaxf(mt, __shfl_xor(mt, 16));
            mt = fmaxf(mt, __shfl_xor(mt, 32));

            float psum = 0.f;
#pragma unroll
            for (int jj = 0; jj < 8; ++jj) {
                float p = __expf(sc[jj] - mt);
                psum += p;
                Ps[row * 72 + cg*8 + jj] = f2bf(p);
            }
            psum += __shfl_xor(psum, 16);
            psum += __shfl_xor(psum, 32);

            float o[16];
#pragma unroll
            for (int i = 0; i < 16; ++i) o[i] = 0.f;

            for (int j = 0; j < 32; ++j) {
                float p = bf2f(Ps[row * 72 + j]);
                if (p != 0.f) {
                    int kv = pidx[(size_t)(s0+row)*NKSP + j];
                    const ushort* vrow = &Vh[(size_t)kv * NDH + cg*16];
#pragma unroll
                    for (int c = 0; c < 2; ++c) {
                        union { bf16x8 v; ushort s[8]; } vv;
                        vv.v = *(const bf16x8*)(vrow + c*8);
#pragma unroll
                        for (int jb = 0; jb < 8; ++jb)
                            o[c*8 + jb] = fmaf(p, bf2f(vv.s[jb]), o[c*8 + jb]);
                    }
                }
            }

            float inv = 1.f / psum;
            ushort* op = OA + ((size_t)b*NS + s0 + row)*ND + h*NDH + cg*16;
#pragma unroll
            for (int i4 = 0; i4 < 4; ++i4) {
                ushort4 v;
                v.x = f2bf(o[i4*4+0]*inv); v.y = f2bf(o[i4*4+1]*inv);
                v.z = f2bf(o[i4*4+2]*inv); v.w = f2bf(o[i4*4+3]*inv);
                *(ushort4*)(op + i4*4) = v;
            }
        }
    }
}

// ---------------------------------------------------------------------------
extern "C" void kernel_launch(void* const* d_in, const int* in_sizes, int n_in,
                              void* d_out, int out_size, void* d_ws, size_t ws_size,
                              hipStream_t stream)
{
    const float* x      = (const float*)d_in[0];
    const int*   pmask  = (const int*)  d_in[1];
    const int*   pidx   = (const int*)  d_in[2];
    const int*   pimask = (const int*)  d_in[3];
    const float* u_prev = (const float*)d_in[4];
    const float* Wq     = (const float*)d_in[5];
    const float* bq     = (const float*)d_in[6];
    const float* Wk     = (const float*)d_in[7];
    const float* bk     = (const float*)d_in[8];
    const float* Wv     = (const float*)d_in[9];
    const float* bv     = (const float*)d_in[10];
    const float* Wo     = (const float*)d_in[11];
    const float* bo     = (const float*)d_in[12];
    float* out = (float*)d_out;

    const size_t QSZ = (size_t)NB * NH * NS * NDH;   // 4,194,304 elements
    const size_t WSZ = (size_t)ND * ND;              // 1,048,576 elements
    ushort* xb  = (ushort*)d_ws;        // bf16 x              (8 MB)
    ushort* Qw  = xb  + QSZ;            // bf16 Q (b,h,s,dh)   (8 MB)
    ushort* Kw  = Qw  + QSZ;            // bf16 K              (8 MB)
    ushort* Vw  = Kw  + QSZ;            // bf16 V              (8 MB)
    ushort* Vtw = Vw  + QSZ;            // bf16 V^T (b,h,dh,s) (8 MB)
    ushort* Awb = Vtw + QSZ;            // bf16 attn out       (8 MB)
    ushort* Wqb = Awb + QSZ;            // bf16 weights (2 MB each)
    ushort* Wkb = Wqb + WSZ;
    ushort* Wvb = Wkb + WSZ;
    ushort* Wob = Wvb + WSZ;
    u64*    bmw = (u64*)(Wob + WSZ);    // packed mask (128 KB)

    f2bf_multi<<<dim3(4096, 6), 256, 0, stream>>>(
        x, Wq, Wk, Wv, Wo, pmask, xb, Wqb, Wkb, Wvb, Wob, bmw);

    gemm_qkv<<<dim3(24, 32), 256, 0, stream>>>(
        xb, Wqb, Wkb, Wvb, bq, bk, bv, Qw, Kw, Vw, Vtw);

    attn_kernel<<<512, 256, 0, stream>>>(
        Qw, Kw, Vw, Vtw, bmw, pidx, pimask, u_prev, Awb);

    gemm_out<<<dim3(ND/128, (NB*NS)/64), 256, 0, stream>>>(Awb, Wob, bo, out);
}

// Round 6
// 225.956 us; speedup vs baseline: 1.2929x; 1.0463x over previous
//
#include <hip/hip_runtime.h>
#include <hip/hip_bf16.h>
#include <cmath>

#define NB 4
#define NS 1024
#define ND 1024
#define NH 16
#define NDH 64
#define NKSP 32
#define SCALE 0.125f      // 1/sqrt(64)
#define LOG2E 1.44269504f
#define SCALE2 (SCALE * LOG2E)

typedef __attribute__((ext_vector_type(8))) short bf16x8;
typedef __attribute__((ext_vector_type(4))) float f32x4;
typedef unsigned long long u64;

#define AS1 __attribute__((address_space(1)))
#define AS3 __attribute__((address_space(3)))

__device__ __forceinline__ void gl_lds16(const void* g, void* l) {
    __builtin_amdgcn_global_load_lds((const AS1 void*)g, (AS3 void*)l, 16, 0, 0);
}

__device__ __forceinline__ ushort f2bf(float f) {
    union { __hip_bfloat16 h; ushort u; } cv;
    cv.h = __float2bfloat16(f);
    return cv.u;
}
__device__ __forceinline__ float bf2f(ushort u) {
    union { unsigned int i; float f; } cv;
    cv.i = ((unsigned int)u) << 16;
    return cv.f;
}
__device__ __forceinline__ float fexp2(float x) {
    return __builtin_amdgcn_exp2f(x);   // v_exp_f32 (base-2)
}

// ---------------------------------------------------------------------------
// y=0: x->bf16 (4096 blocks); y=1..4: W->bf16 (1024 blocks);
// y=5: pack pmask into bitwords (4096 blocks, one wave per u64 word).
// ---------------------------------------------------------------------------
__global__ __launch_bounds__(256)
void f2bf_multi(const float* __restrict__ x,
                const float* __restrict__ w0, const float* __restrict__ w1,
                const float* __restrict__ w2, const float* __restrict__ w3,
                const int* __restrict__ pm,
                ushort* __restrict__ xo,
                ushort* __restrict__ o0, ushort* __restrict__ o1,
                ushort* __restrict__ o2, ushort* __restrict__ o3,
                u64* __restrict__ bm)
{
    int y = blockIdx.y;
    if (y == 5) {
        int word = blockIdx.x * 4 + (threadIdx.x >> 6);
        int lane = threadIdx.x & 63;
        int row  = word >> 4, wcol = word & 15;
        int v = pm[(size_t)row * NS + wcol * 64 + lane];
        u64 b = __ballot(v != 0);
        if (lane == 0) bm[word] = b;
        return;
    }
    const float* src; ushort* dst; int nblk;
    if (y == 0)      { src = x;  dst = xo; nblk = 4096; }
    else if (y == 1) { src = w0; dst = o0; nblk = 1024; }
    else if (y == 2) { src = w1; dst = o1; nblk = 1024; }
    else if (y == 3) { src = w2; dst = o2; nblk = 1024; }
    else             { src = w3; dst = o3; nblk = 1024; }
    if (blockIdx.x >= (unsigned)nblk) return;
    int i = (blockIdx.x * 256 + threadIdx.x) * 4;
    float4 v = *(const float4*)&src[i];
    ushort4 o;
    o.x = f2bf(v.x); o.y = f2bf(v.y); o.z = f2bf(v.z); o.w = f2bf(v.w);
    *(ushort4*)&dst[i] = o;
}

// ---------------------------------------------------------------------------
// Fused QKV GEMM (direct-scatter epilogue; V also writes Vt).
// grid (24,32): blockIdx.x: [0,8)=Q [8,16)=K [16,24)=V.
// ---------------------------------------------------------------------------
__global__ __launch_bounds__(256)
void gemm_qkv(const ushort* __restrict__ xb,
              const ushort* __restrict__ Wqb, const ushort* __restrict__ Wkb,
              const ushort* __restrict__ Wvb,
              const float* __restrict__ bq, const float* __restrict__ bk,
              const float* __restrict__ bv,
              ushort* __restrict__ Qo, ushort* __restrict__ Ko,
              ushort* __restrict__ Vo, ushort* __restrict__ Vto)
{
    constexpr int K = ND;
    __shared__ __attribute__((aligned(16))) ushort As[128 * 32];
    __shared__ __attribute__((aligned(16))) ushort Bs[128 * 32];

    const int tid  = threadIdx.x;
    const int lane = tid & 63, w = tid >> 6;
    const int wm = w >> 1, wn = w & 1;
    const int which = blockIdx.x >> 3;
    const int n0 = (blockIdx.x & 7) * 128;
    const int m0 = blockIdx.y * 128;
    const int quad = lane >> 4, l16 = lane & 15;

    const ushort* W = (which == 0) ? Wqb : (which == 1) ? Wkb : Wvb;
    const float* bias = (which == 0) ? bq : (which == 1) ? bk : bv;
    ushort* Out = (which == 0) ? Qo : (which == 1) ? Ko : Vo;

    f32x4 acc[4][4] = {};

    for (int k0 = 0; k0 < K; k0 += 32) {
        __syncthreads();
#pragma unroll
        for (int u = 0; u < 2; ++u) {
            int t0 = u * 256 + w * 64;
            int t  = t0 + lane;
            int row = t >> 2, kc = (t & 3) * 8;
            gl_lds16(xb + (size_t)(m0 + row) * K + k0 + kc, &As[t0 * 8]);
            gl_lds16(W  + (size_t)(n0 + row) * K + k0 + kc, &Bs[t0 * 8]);
        }
        __syncthreads();

        bf16x8 af[4], bfr[4];
#pragma unroll
        for (int mt = 0; mt < 4; ++mt)
            af[mt] = *(const bf16x8*)&As[(wm*64 + mt*16 + l16) * 32 + quad*8];
#pragma unroll
        for (int nt = 0; nt < 4; ++nt)
            bfr[nt] = *(const bf16x8*)&Bs[(wn*64 + nt*16 + l16) * 32 + quad*8];
#pragma unroll
        for (int mt = 0; mt < 4; ++mt)
#pragma unroll
            for (int nt = 0; nt < 4; ++nt)
                acc[mt][nt] = __builtin_amdgcn_mfma_f32_16x16x32_bf16(
                    af[mt], bfr[nt], acc[mt][nt], 0, 0, 0);
    }

#pragma unroll
    for (int nt = 0; nt < 4; ++nt) {
        int n = n0 + wn*64 + nt*16 + l16;
        float bz = bias[n];
        int hh = n >> 6, dh = n & 63;
#pragma unroll
        for (int mt = 0; mt < 4; ++mt) {
#pragma unroll
            for (int rg = 0; rg < 4; ++rg) {
                int m = m0 + wm*64 + mt*16 + quad*4 + rg;
                int b = m >> 10, s = m & (NS - 1);
                ushort val = f2bf(acc[mt][nt][rg] + bz);
                Out[(((size_t)(b*NH + hh))*NS + s)*NDH + dh] = val;
                if (which == 2)
                    Vto[(((size_t)(b*NH + hh))*NDH + dh)*NS + s] = val;
            }
        }
    }
}

// ---------------------------------------------------------------------------
// Output GEMM: 64x128 tile -> 512 blocks.
// ---------------------------------------------------------------------------
__global__ __launch_bounds__(256)
void gemm_out(const ushort* __restrict__ A, const ushort* __restrict__ W,
              const float* __restrict__ bias, float* __restrict__ Cout)
{
    constexpr int K = ND;
    __shared__ __attribute__((aligned(16))) ushort As[64 * 32];
    __shared__ __attribute__((aligned(16))) ushort Bs[128 * 32];

    const int tid  = threadIdx.x;
    const int lane = tid & 63, w = tid >> 6;
    const int wm = w & 1, wn = w >> 1;
    const int m0 = blockIdx.y * 64, n0 = blockIdx.x * 128;
    const int quad = lane >> 4, l16 = lane & 15;

    f32x4 acc[2][4] = {};

    for (int k0 = 0; k0 < K; k0 += 32) {
        __syncthreads();
        {
            int t0 = w * 64;
            int t  = t0 + lane;
            int row = t >> 2, kc = (t & 3) * 8;
            gl_lds16(A + (size_t)(m0 + row) * K + k0 + kc, &As[t0 * 8]);
        }
#pragma unroll
        for (int u = 0; u < 2; ++u) {
            int t0 = u * 256 + w * 64;
            int t  = t0 + lane;
            int row = t >> 2, kc = (t & 3) * 8;
            gl_lds16(W + (size_t)(n0 + row) * K + k0 + kc, &Bs[t0 * 8]);
        }
        __syncthreads();

        bf16x8 af[2], bfr[4];
#pragma unroll
        for (int mt = 0; mt < 2; ++mt)
            af[mt] = *(const bf16x8*)&As[(wm*32 + mt*16 + l16) * 32 + quad*8];
#pragma unroll
        for (int nt = 0; nt < 4; ++nt)
            bfr[nt] = *(const bf16x8*)&Bs[(wn*64 + nt*16 + l16) * 32 + quad*8];
#pragma unroll
        for (int mt = 0; mt < 2; ++mt)
#pragma unroll
            for (int nt = 0; nt < 4; ++nt)
                acc[mt][nt] = __builtin_amdgcn_mfma_f32_16x16x32_bf16(
                    af[mt], bfr[nt], acc[mt][nt], 0, 0, 0);
    }

#pragma unroll
    for (int nt = 0; nt < 4; ++nt) {
        int n = n0 + wn*64 + nt*16 + l16;
        float bz = bias[n];
#pragma unroll
        for (int mt = 0; mt < 2; ++mt) {
#pragma unroll
            for (int rg = 0; rg < 4; ++rg) {
                int m = m0 + wm*32 + mt*16 + quad*4 + rg;
                Cout[(size_t)m * ND + n] = acc[mt][nt][rg] + bz;
            }
        }
    }
}

// ---------------------------------------------------------------------------
// MFMA flash attention, round 6 (= round-5 design; r5 bench was an infra
// failure — container died twice with no pytest/correctness error; kernel
// re-audited: no divergent barrier, bijective block map, LDS in bounds,
// swizzle round-trip exact, no OOB gather).
// Post-mortem r0/r3/r4: three different K/V feeds -> identical 82-83us,
// so the feed is NOT the bottleneck. Occupancy 16.5% (vs 25% resident-max)
// says CUs idle: sparse-batch blocks finish ~4x early and dense work is
// serialized on few waves (1-2/SIMD) with a long per-wave chain (32 STEPs).
// This round:
//  (1) 64-row blocks, 4 waves = (wq rows) x (wk kt-parity). P has NO
//      running max (exp2 of bounded scores), so K-partials are exactly
//      additive: wk=0 does even kt, wk=1 odd kt; combine o/l once at the
//      end via LDS. Serial chain halves (16 STEPs/wave); per-wave ILP
//      (32 rows, qh loop) preserved — unlike r1/r2.
//  (2) 1024 blocks, 4 slots/CU, b = ((id>>3)+(id>>8))&3 rotates the batch
//      each slot -> every CU gets all 4 batches once, ANY dense subset
//      balances. Head->XCD clustering kept (xcd = id&7 in head index).
//  (3) K staged in LDS (kills r1's L1-thrash mechanism); V direct-gather
//      (r0-r4 proved staging V is perf-neutral). Sparse path: selects
//      instead of divergent branches; PV j-loop unrolled, branch dropped.
// LDS = Ps 18432 + MW 8192 + KK 32768 = 58 KB -> 2 blocks/CU.
// ---------------------------------------------------------------------------

// Stage the kt-pair (PT, PT+1) K-tiles into KK[BUF] (1024 16B chunks,
// 4 waves x 4 gl_lds). Source chunk-swizzled sub^=(row&7) (rule #21).
#define STAGE(BUF, PT)                                                        \
    _Pragma("unroll")                                                         \
    for (int u = 0; u < 4; ++u) {                                             \
        int cb = w * 256 + u * 64;                                            \
        int c  = cb + lane;                                                   \
        int wk2 = c >> 9, c2 = c & 511;                                       \
        int row = c2 >> 3, sub = c2 & 7;                                      \
        const ushort* src = Kh + (((size_t)(((PT) + wk2)*64 + row)) << 6)     \
                               + ((sub ^ (row & 7)) << 3);                    \
        gl_lds16(src, (ushort*)KK + (BUF)*8192 + (size_t)cb * 8);             \
    }

// K fragments from LDS (swizzled chunk), V fragments direct from global.
#define LOADKV(KF, VF, BUF, KT)                                               \
    _Pragma("unroll")                                                         \
    for (int nt = 0; nt < 4; ++nt)                                            \
        _Pragma("unroll")                                                     \
        for (int kk = 0; kk < 2; ++kk) {                                      \
            int rowk = nt*16 + l16;                                           \
            int ck = (kk*4 + quad) ^ (l16 & 7);                               \
            KF[nt][kk] = *(const bf16x8*)                                     \
                &((ushort*)KK)[(BUF)*8192 + wk*4096 + rowk*64 + ck*8];        \
            VF[nt][kk] = *(const bf16x8*)                                     \
                &Vth[(size_t)(nt*16 + l16) * NS + (KT)*64 + kk*32 + quad*8];  \
        }

// One K-tile step: both qh halves of this wave's 32 rows.
#define STEP(KT, KF, VF)                                                      \
    _Pragma("unroll")                                                         \
    for (int qh = 0; qh < 2; ++qh) {                                          \
        const int qrow = wq*32 + qh*16 + l16;                                 \
        u64 wqm = MW[(KT)*64 + qrow] >> (quad * 4);                           \
        f32x4 s_acc[4] = {};                                                  \
        __builtin_amdgcn_s_setprio(1);                                        \
        _Pragma("unroll")                                                     \
        for (int nt = 0; nt < 4; ++nt)                                        \
            _Pragma("unroll")                                                 \
            for (int kk = 0; kk < 2; ++kk)                                    \
                s_acc[nt] = __builtin_amdgcn_mfma_f32_16x16x32_bf16(          \
                    KF[nt][kk], qf[qh][kk], s_acc[nt], 0, 0, 0);              \
        __builtin_amdgcn_s_setprio(0);                                        \
        _Pragma("unroll")                                                     \
        for (int nt = 0; nt < 4; ++nt) {                                      \
            ushort4 pk;                                                       \
            float p0 = fexp2(fmaf(s_acc[nt][0], SCALE2,                       \
                 ((wqm >> (nt*16 + 0)) & 1ULL) ? 0.f : nlam2));               \
            float p1 = fexp2(fmaf(s_acc[nt][1], SCALE2,                       \
                 ((wqm >> (nt*16 + 1)) & 1ULL) ? 0.f : nlam2));               \
            float p2 = fexp2(fmaf(s_acc[nt][2], SCALE2,                       \
                 ((wqm >> (nt*16 + 2)) & 1ULL) ? 0.f : nlam2));               \
            float p3 = fexp2(fmaf(s_acc[nt][3], SCALE2,                       \
                 ((wqm >> (nt*16 + 3)) & 1ULL) ? 0.f : nlam2));               \
            pk.x = f2bf(p0); pk.y = f2bf(p1);                                 \
            pk.z = f2bf(p2); pk.w = f2bf(p3);                                 \
            *(ushort4*)&Ps[wk][qrow*72 + nt*16 + quad*4] = pk;                \
        }                                                                     \
        bf16x8 pf[2];                                                         \
        _Pragma("unroll")                                                     \
        for (int kk = 0; kk < 2; ++kk)                                        \
            pf[kk] = *(const bf16x8*)&Ps[wk][qrow*72 + kk*32 + quad*8];       \
        __builtin_amdgcn_s_setprio(1);                                        \
        _Pragma("unroll")                                                     \
        for (int kk = 0; kk < 2; ++kk) {                                      \
            l_acc[qh] = __builtin_amdgcn_mfma_f32_16x16x32_bf16(              \
                pf[kk], ones.v, l_acc[qh], 0, 0, 0);                          \
            _Pragma("unroll")                                                 \
            for (int nt = 0; nt < 4; ++nt)                                    \
                o_acc[qh][nt] = __builtin_amdgcn_mfma_f32_16x16x32_bf16(      \
                    pf[kk], VF[nt][kk], o_acc[qh][nt], 0, 0, 0);              \
        }                                                                     \
        __builtin_amdgcn_s_setprio(0);                                        \
    }

__global__ __launch_bounds__(256, 2)
void attn_kernel(const ushort* __restrict__ Qb, const ushort* __restrict__ Kb,
                 const ushort* __restrict__ Vb, const ushort* __restrict__ Vt,
                 const u64* __restrict__ bm,
                 const int* __restrict__ pidx, const int* __restrict__ pimask,
                 const float* __restrict__ u_prev, ushort* __restrict__ OA)
{
    __shared__ __attribute__((aligned(16))) ushort Ps[2][64 * 72];
    __shared__ __attribute__((aligned(16))) u64    MW[16 * 64];
    __shared__ __attribute__((aligned(16))) ushort KK[2][2][64 * 64];

    const int tid  = threadIdx.x;
    const int lane = tid & 63, w = tid >> 6;      // 4 waves
    const int quad = lane >> 4, l16 = lane & 15;
    const int wq = w & 1, wk = w >> 1;            // row-half / kt-parity

    const int id    = blockIdx.x;                 // 0..1023
    const int xcd   = id & 7;
    const int b     = ((id >> 3) + (id >> 8)) & 3;  // batch rotates per CU slot
    const int hb    = (id >> 5) & 1;
    const int qtile = (id >> 6) & 15;             // 16 tiles of 64 rows
    const int h     = hb * 8 + xcd;               // head -> fixed XCD
    const int s0    = qtile * 64;

    const float lam = 10.0f * __expf(-5.0f * u_prev[b]);
    const bool sparse = (lam >= 1.0f);

    const size_t bh = (size_t)b * NH + h;
    const ushort* Qh  = Qb + bh * NS * NDH;
    const ushort* Kh  = Kb + bh * NS * NDH;
    const ushort* Vh  = Vb + bh * NS * NDH;
    const ushort* Vth = Vt + bh * NDH * NS;

    if (!sparse) {
        const float nlam2 = -lam * LOG2E;   // base-2 bias

        // stage kt-pair 0 + mask words MW[kt][row] (rows s0..s0+63)
        STAGE(0, 0);
#pragma unroll
        for (int u = 0; u < 4; ++u) {
            int idx = u * 256 + tid;              // 0..1023
            int row = idx >> 4, wd = idx & 15;
            MW[wd * 64 + row] = bm[(size_t)s0 * 16 + idx];
        }

        // Q fragments (B-operand = Q^T) for this wave's 32 rows
        bf16x8 qf[2][2];
#pragma unroll
        for (int qh = 0; qh < 2; ++qh)
#pragma unroll
            for (int kk = 0; kk < 2; ++kk)
                qf[qh][kk] = *(const bf16x8*)
                    &Qh[(size_t)(s0 + wq*32 + qh*16 + l16) * NDH + kk*32 + quad*8];

        union { bf16x8 v; ushort s[8]; } ones;
#pragma unroll
        for (int i = 0; i < 8; ++i) ones.s[i] = 0x3F80;  // bf16 1.0

        f32x4 o_acc[2][4] = {};
        f32x4 l_acc[2] = {};

        __syncthreads();   // pair 0 + MW visible

        int cur = 0;
        for (int t = 0; t < 8; ++t) {
            if (t + 1 < 8) STAGE(cur ^ 1, 2*(t + 1));
            bf16x8 kf[4][2], vf[4][2];
            const int kt = 2*t + wk;              // this wave's kt parity
            LOADKV(kf, vf, cur, kt);
            STEP(kt, kf, vf);
            __syncthreads();
            cur ^= 1;
        }

        // ----- combine wk partials (o,l additive: no max normalization) ----
        float* POUT = (float*)KK;                 // KK dead after loop
        if (wk == 1) {
#pragma unroll
            for (int qh = 0; qh < 2; ++qh) {
#pragma unroll
                for (int nt = 0; nt < 4; ++nt)
#pragma unroll
                    for (int rg = 0; rg < 4; ++rg)
                        POUT[(wq*40 + qh*16 + nt*4 + rg)*64 + lane] =
                            o_acc[qh][nt][rg];
#pragma unroll
                for (int rg = 0; rg < 4; ++rg)
                    POUT[(wq*40 + 32 + qh*4 + rg)*64 + lane] = l_acc[qh][rg];
            }
        }
        __syncthreads();
        if (wk == 0) {
#pragma unroll
            for (int qh = 0; qh < 2; ++qh) {
#pragma unroll
                for (int nt = 0; nt < 4; ++nt)
#pragma unroll
                    for (int rg = 0; rg < 4; ++rg)
                        o_acc[qh][nt][rg] +=
                            POUT[(wq*40 + qh*16 + nt*4 + rg)*64 + lane];
#pragma unroll
                for (int rg = 0; rg < 4; ++rg)
                    l_acc[qh][rg] += POUT[(wq*40 + 32 + qh*4 + rg)*64 + lane];
            }
            // epilogue (row=query quad*4+rg, col=dh nt*16+l16)
#pragma unroll
            for (int qh = 0; qh < 2; ++qh) {
                float inv[4];
#pragma unroll
                for (int rg = 0; rg < 4; ++rg) inv[rg] = 1.f / l_acc[qh][rg];
#pragma unroll
                for (int nt = 0; nt < 4; ++nt)
#pragma unroll
                    for (int rg = 0; rg < 4; ++rg) {
                        int m = wq*32 + qh*16 + quad*4 + rg;
                        OA[((size_t)b*NS + s0 + m)*ND + h*NDH + nt*16 + l16] =
                            f2bf(o_acc[qh][nt][rg] * inv[rg]);
                    }
            }
        }
    } else {
        // ---------------- sparse path (fp32 scalar, bf16 inputs) ----------
        const int r2  = lane & 15;
        const int cg  = lane >> 4;
        {
            const int row = w*16 + r2;            // 0..63

            float qreg[64];
            {
                const ushort* qp = Qh + (size_t)(s0 + row) * NDH;
#pragma unroll
                for (int c = 0; c < 8; ++c) {
                    union { bf16x8 v; ushort s[8]; } qv;
                    qv.v = *(const bf16x8*)(qp + c*8);
#pragma unroll
                    for (int j = 0; j < 8; ++j) qreg[c*8 + j] = bf2f(qv.s[j]);
                }
            }

            // scores: unconditional gather + select (no divergent branch)
            float sc[8];
#pragma unroll
            for (int jj = 0; jj < 8; ++jj) {
                int j  = cg*8 + jj;
                int mv = pimask[(size_t)(s0+row)*NKSP + j];
                int kv = pidx[(size_t)(s0+row)*NKSP + j];
                const ushort* krow = &Kh[(size_t)kv * NDH];
                float acc = 0.f;
#pragma unroll
                for (int c = 0; c < 8; ++c) {
                    union { bf16x8 v; ushort s[8]; } kk;
                    kk.v = *(const bf16x8*)(krow + c*8);
#pragma unroll
                    for (int jb = 0; jb < 8; ++jb)
                        acc = fmaf(qreg[c*8 + jb], bf2f(kk.s[jb]), acc);
                }
                sc[jj] = mv ? acc * SCALE : -INFINITY;
            }
            float mt = sc[0];
#pragma unroll
            for (int jj = 1; jj < 8; ++jj) mt = fmaxf(mt, sc[jj]);
            mt = fmaxf(mt, __shfl_xor(mt, 16));
            mt = fmaxf(mt, __shfl_xor(mt, 32));

            float psum = 0.f;
#pragma unroll
            for (int jj = 0; jj < 8; ++jj) {
                float p = __expf(sc[jj] - mt);
                psum += p;
                Ps[0][row * 72 + cg*8 + jj] = f2bf(p);
            }
            psum += __shfl_xor(psum, 16);
            psum += __shfl_xor(psum, 32);

            float o[16];
#pragma unroll
            for (int i = 0; i < 16; ++i) o[i] = 0.f;

            // PV: p=0 contributes 0 -> no branch; unroll for load pipelining
#pragma unroll 4
            for (int j = 0; j < 32; ++j) {
                float p = bf2f(Ps[0][row * 72 + j]);
                int kv = pidx[(size_t)(s0+row)*NKSP + j];
                const ushort* vrow = &Vh[(size_t)kv * NDH + cg*16];
#pragma unroll
                for (int c = 0; c < 2; ++c) {
                    union { bf16x8 v; ushort s[8]; } vv;
                    vv.v = *(const bf16x8*)(vrow + c*8);
#pragma unroll
                    for (int jb = 0; jb < 8; ++jb)
                        o[c*8 + jb] = fmaf(p, bf2f(vv.s[jb]), o[c*8 + jb]);
                }
            }

            float inv = 1.f / psum;
            ushort* op = OA + ((size_t)b*NS + s0 + row)*ND + h*NDH + cg*16;
#pragma unroll
            for (int i4 = 0; i4 < 4; ++i4) {
                ushort4 v;
                v.x = f2bf(o[i4*4+0]*inv); v.y = f2bf(o[i4*4+1]*inv);
                v.z = f2bf(o[i4*4+2]*inv); v.w = f2bf(o[i4*4+3]*inv);
                *(ushort4*)(op + i4*4) = v;
            }
        }
    }
}

// ---------------------------------------------------------------------------
extern "C" void kernel_launch(void* const* d_in, const int* in_sizes, int n_in,
                              void* d_out, int out_size, void* d_ws, size_t ws_size,
                              hipStream_t stream)
{
    const float* x      = (const float*)d_in[0];
    const int*   pmask  = (const int*)  d_in[1];
    const int*   pidx   = (const int*)  d_in[2];
    const int*   pimask = (const int*)  d_in[3];
    const float* u_prev = (const float*)d_in[4];
    const float* Wq     = (const float*)d_in[5];
    const float* bq     = (const float*)d_in[6];
    const float* Wk     = (const float*)d_in[7];
    const float* bk     = (const float*)d_in[8];
    const float* Wv     = (const float*)d_in[9];
    const float* bv     = (const float*)d_in[10];
    const float* Wo     = (const float*)d_in[11];
    const float* bo     = (const float*)d_in[12];
    float* out = (float*)d_out;

    const size_t QSZ = (size_t)NB * NH * NS * NDH;   // 4,194,304 elements
    const size_t WSZ = (size_t)ND * ND;              // 1,048,576 elements
    ushort* xb  = (ushort*)d_ws;        // bf16 x              (8 MB)
    ushort* Qw  = xb  + QSZ;            // bf16 Q (b,h,s,dh)   (8 MB)
    ushort* Kw  = Qw  + QSZ;            // bf16 K              (8 MB)
    ushort* Vw  = Kw  + QSZ;            // bf16 V              (8 MB)
    ushort* Vtw = Vw  + QSZ;            // bf16 V^T (b,h,dh,s) (8 MB)
    ushort* Awb = Vtw + QSZ;            // bf16 attn out       (8 MB)
    ushort* Wqb = Awb + QSZ;            // bf16 weights (2 MB each)
    ushort* Wkb = Wqb + WSZ;
    ushort* Wvb = Wkb + WSZ;
    ushort* Wob = Wvb + WSZ;
    u64*    bmw = (u64*)(Wob + WSZ);    // packed mask (128 KB)

    f2bf_multi<<<dim3(4096, 6), 256, 0, stream>>>(
        x, Wq, Wk, Wv, Wo, pmask, xb, Wqb, Wkb, Wvb, Wob, bmw);

    gemm_qkv<<<dim3(24, 32), 256, 0, stream>>>(
        xb, Wqb, Wkb, Wvb, bq, bk, bv, Qw, Kw, Vw, Vtw);

    attn_kernel<<<1024, 256, 0, stream>>>(
        Qw, Kw, Vw, Vtw, bmw, pidx, pimask, u_prev, Awb);

    gemm_out<<<dim3(ND/128, (NB*NS)/64), 256, 0, stream>>>(Awb, Wob, bo, out);
}